// Round 15
// baseline (503.082 us; speedup 1.0000x reference)
//
#include <hip/hip_runtime.h>
#include <hip/hip_bf16.h>

// Problem dims (fixed): T=256, B=8, H=128, IN=256
#define T_LEN 256
#define CHUNK 8
#define NCHUNK (T_LEN / CHUNK)

typedef _Float16 f16x8 __attribute__((ext_vector_type(8)));
typedef float f32x4 __attribute__((ext_vector_type(4)));

__device__ __forceinline__ float fsig(float x) {
  return __builtin_amdgcn_rcpf(1.f + __expf(-x));
}
__device__ __forceinline__ float ftanhf(float x) {
  return fmaf(-2.f, __builtin_amdgcn_rcpf(1.f + __expf(2.f * x)), 1.f);
}

#define MFMA16(a,b,c) __builtin_amdgcn_mfma_f32_16x16x32_f16(a, b, c, 0, 0, 0)
#define PIN(x) asm volatile("" : "+v"(*reinterpret_cast<f32x4*>(&(x))))

// ---------------- weight reformat (+ flag zero) ----------------
__global__ void k_prep(const float* __restrict__ WvP, const float* __restrict__ WvPb,
                       const float* __restrict__ gatew,
                       const float* __restrict__ Wih, const float* __restrict__ Whh,
                       float* __restrict__ WvPT, float* __restrict__ WvPbT,
                       float* __restrict__ gwT, float* __restrict__ Wih0T,
                       _Float16* __restrict__ Wx, _Float16* __restrict__ Wh,
                       unsigned* __restrict__ flags) {
  int n = blockIdx.x*blockDim.x + threadIdx.x;
  int NT = gridDim.x*blockDim.x;
  if (n < 256) flags[n] = 0u;
  for (int k = n; k < 256*128; k += NT) {
    int i = k >> 7, h = k & 127;
    WvPT[k]  = WvP[h*256 + i];
    WvPbT[k] = WvPb[h*256 + i];
  }
  for (int k = n; k < 256*256; k += NT) {
    int dd = k >> 8, e = k & 255;
    gwT[k] = gatew[e*256 + dd];
  }
  for (int k = n; k < 256*768; k += NT) {
    int i = k / 768, doo = k % 768;
    Wih0T[k] = Wih[(size_t)doo*256 + i];
  }
  for (int k = n; k < 6*384*128; k += NT) {
    Wh[k] = (_Float16)Whh[k];           // flat [c][o][128]
  }
  for (int k = n; k < 4*384*256; k += NT) {
    Wx[k] = (_Float16)Wih[(size_t)2*384*256 + k];  // cells 2..5
  }
}

// ---------------- prep/pbar projections (prior kernel) ----------------
__global__ __launch_bounds__(256) void k_prep_pbar(
    const float* __restrict__ P, const float* __restrict__ WvPT,
    const float* __restrict__ WvPbT, float* __restrict__ prepT,
    float* __restrict__ pbar) {
  __shared__ float Pl[4*256];
  int R0 = blockIdx.x * 4, tid = threadIdx.x;
  for (int k = tid; k < 1024; k += 256) Pl[k] = P[(size_t)R0*256 + k];
  __syncthreads();
  int h = tid & 127;
  const float* Wt = (tid < 128) ? WvPT : WvPbT;
  float acc[4] = {0,0,0,0};
  for (int i = 0; i < 256; ++i) {
    float w = Wt[i*128 + h];
    acc[0] += Pl[i]*w; acc[1] += Pl[256+i]*w;
    acc[2] += Pl[512+i]*w; acc[3] += Pl[768+i]*w;
  }
  #pragma unroll
  for (int r = 0; r < 4; ++r) {
    int R = R0 + r, t = R >> 3, b = R & 7;
    if (tid < 128) prepT[((size_t)b*128 + h)*256 + t] = acc[r];
    else           pbar[(size_t)R*128 + h] = acc[r];
  }
}

// ---------------- fused persistent kernel --------------------------------
// wg 0..5    : CELL (r13-proven loop; all layers chunk-gated; gi via atomics)
// wg 6..37   : GX   (r12-proven chunk GEMM, off the recurrence path)
// wg 38..165 : ATTN (2 instances/WG x 2 rounds = 512 (b,q0) instances;
//              raises per-q0 counters flags[104+q0/4] -> 8)
// wg 166..197: GI0  (one 8-t chunk each; waits q0 counters; computes
//              ug@Wih0^T + bias; raises flags[72+tc])
// flags: [0..5] cell h-chunk; [8+(l-1)*32+tc] gi1/gi2 chunk;
//        [72+tc] gi0 chunk; [104+ci] attn q0-group counters.
__global__ __launch_bounds__(512, 1) void k_fused(
    const _Float16* __restrict__ Wx, const _Float16* __restrict__ Wh,
    const float* __restrict__ prepT, const float* __restrict__ pbar,
    const float* __restrict__ vw, const float* __restrict__ gwT,
    const float* __restrict__ Wih0T, float* __restrict__ ug,
    float* __restrict__ gi0, float* __restrict__ gi1, float* __restrict__ gi2,
    const float* __restrict__ bih, const float* __restrict__ bhh,
    unsigned long long* Hbuf, float* __restrict__ out, unsigned* flags)
{
  const int wg = blockIdx.x;
  const int tid = threadIdx.x;
  const int w = tid >> 6, lane = tid & 63;
  const int lo = lane & 15, hi = lane >> 4;

  __shared__ char LDSU[36864];

  if (wg < 6) {
    // ======================= CELL role =======================
    const int c = wg, l = c >> 1, d = c & 1;
    _Float16* hlds = (_Float16*)(LDSU + 32768);   // [2][8*128]
    char* SL = LDSU;

    { f16x8 z = {0,0,0,0,0,0,0,0};
      for (int p = tid; p < 256; p += 512) ((f16x8*)hlds)[p] = z; }

    f16x8 bh[3][4];
    #pragma unroll
    for (int nt = 0; nt < 3; ++nt) {
      int o = 16*(w + 8*nt) + lo;
      #pragma unroll
      for (int ks = 0; ks < 4; ++ks)
        bh[nt][ks] = *(const f16x8*)(Wh + ((size_t)c*384 + o)*128 + 32*ks + 8*hi);
    }
    #pragma unroll
    for (int nt = 0; nt < 3; ++nt)
      #pragma unroll
      for (int ks = 0; ks < 4; ++ks)
        PIN(bh[nt][ks]);

    const int hidx = 16*w + lo;
    const float b_hn = bhh[(size_t)c*384 + 256 + hidx];
    const int b0 = 4*(hi & 1);

    const unsigned long long* gatom = (const unsigned long long*)
        ((l == 0) ? gi0 : (l == 1) ? gi1 : gi2) + (size_t)(d*384)*4;
    unsigned* fg = flags + 8 + (l > 0 ? (l-1)*32 : 0);

    f32x4 gA0,gA1,gA2, gB0,gB1,gB2;
    auto LD = [&](int t, f32x4& x0, f32x4& x1, f32x4& x2) {
      const unsigned long long* g = gatom + (size_t)t*3072 + (b0 >> 1);
      #pragma unroll
      for (int a = 0; a < 3; ++a) {
        size_t ix = (size_t)(a*128 + hidx)*4;
        unsigned long long u0 = __hip_atomic_load(g + ix,
            __ATOMIC_RELAXED, __HIP_MEMORY_SCOPE_AGENT);
        unsigned long long u1 = __hip_atomic_load(g + ix + 1,
            __ATOMIC_RELAXED, __HIP_MEMORY_SCOPE_AGENT);
        f32x4 v;
        ((unsigned long long*)&v)[0] = u0;
        ((unsigned long long*)&v)[1] = u1;
        if (a == 0) x0 = v; else if (a == 1) x1 = v; else x2 = v;
      }
    };

    float hp[4] = {0,0,0,0};
    __syncthreads();

    for (int tc = 0; tc < NCHUNK; ++tc) {
      if (tid == 0) {
        if (l == 0) {
          while (__hip_atomic_load(flags + 72 + tc, __ATOMIC_RELAXED,
                                   __HIP_MEMORY_SCOPE_AGENT) == 0u)
            __builtin_amdgcn_s_sleep(2);
        } else {
          while (__hip_atomic_load(fg + tc, __ATOMIC_RELAXED,
                                   __HIP_MEMORY_SCOPE_AGENT) == 0u)
            __builtin_amdgcn_s_sleep(2);
        }
        __builtin_amdgcn_fence(__ATOMIC_ACQUIRE, "agent");
      }
      __syncthreads();
      // depth-2 prefetch fill
      LD(tc*CHUNK,     gA0, gA1, gA2);
      LD(tc*CHUNK + 1, gB0, gB1, gB2);

      #pragma unroll
      for (int tt = 0; tt < CHUNK; ++tt) {
        const int t = tc*CHUNK + tt;
        f32x4 ax0, ax1, ax2;
        if (!(tt & 1)) {
          ax0 = gA0; ax1 = gA1; ax2 = gA2;
          if (tt + 2 < CHUNK) LD(t + 2, gA0, gA1, gA2);
        } else {
          ax0 = gB0; ax1 = gB1; ax2 = gB2;
          if (tt + 2 < CHUNK) LD(t + 2, gB0, gB1, gB2);
        }
        // h-part MFMAs
        f32x4 ah0 = {0,0,0,0}, ah1 = {0,0,0,0}, ah2 = {0,0,0,0};
        {
          const char* hb = (const char*)hlds + (t & 1)*2048;
          f16x8 a[4];
          #pragma unroll
          for (int ks = 0; ks < 4; ++ks) {
            int byte = ((lo & 7)*256 + (32*ks + 8*hi)*2) ^ ((lo & 7) << 4);
            a[ks] = *(const f16x8*)(hb + byte);
          }
          #pragma unroll
          for (int ks = 0; ks < 4; ++ks) {
            ah0 = MFMA16(a[ks], bh[0][ks], ah0);
            ah1 = MFMA16(a[ks], bh[1][ks], ah1);
            ah2 = MFMA16(a[ks], bh[2][ks], ah2);
          }
        }
        // slim combine
        float hn[4];
        #pragma unroll
        for (int q = 0; q < 4; ++q) {
          float r  = fsig(ax0[q] + ah0[q]);
          float z  = fsig(ax1[q] + ah1[q]);
          float nn = ftanhf(fmaf(r, ah2[q] + b_hn, ax2[q]));
          hn[q] = fmaf(z, hp[q] - nn, nn);
          hp[q] = hn[q];
        }
        // write h + stage output
        if (lane < 32) {
          char* hb2 = (char*)hlds + ((t + 1) & 1)*2048;
          #pragma unroll
          for (int q = 0; q < 4; ++q) {
            int b = 4*hi + q;
            int byte = (b*256 + hidx*2) ^ (b << 4);
            *(_Float16*)(hb2 + byte) = (_Float16)hn[q];
            if (l < 2) *(_Float16*)(SL + (tt*8 + b)*256 + hidx*2) = (_Float16)hn[q];
            else       *(float*)   (SL + (tt*8 + b)*512 + hidx*4) = hn[q];
          }
        }
        asm volatile("s_waitcnt lgkmcnt(0)" ::: "memory");
        __builtin_amdgcn_s_barrier();
        __builtin_amdgcn_sched_barrier(0);
      }

      // chunk flush
      if (l < 2) {
        #pragma unroll
        for (int i = 0; i < 4; ++i) {
          int u = i*512 + tid;                  // 2048 8B units
          int tt2 = u >> 8, b = (u >> 5) & 7, pu = u & 31;
          unsigned long long v = *(const unsigned long long*)
              (SL + (tt2*8 + b)*256 + pu*8);
          __hip_atomic_store(Hbuf + (((size_t)c) << 16)
                                  + (size_t)(tc*CHUNK + tt2)*256 + b*32 + pu,
                             v, __ATOMIC_RELAXED, __HIP_MEMORY_SCOPE_AGENT);
        }
        asm volatile("s_waitcnt vmcnt(0)" ::: "memory");
        __syncthreads();
        if (tid == 0)
          __hip_atomic_store(flags + c, (unsigned)(tc + 1),
                             __ATOMIC_RELEASE, __HIP_MEMORY_SCOPE_AGENT);
      } else {
        #pragma unroll
        for (int i = 0; i < 4; ++i) {
          int u = i*512 + tid;                  // 2048 16B units
          int tt2 = u >> 8, b = (u >> 5) & 7, cc = u & 31;
          f32x4 v = *(const f32x4*)(SL + (tt2*8 + b)*512 + cc*16);
          *(f32x4*)(out + (((size_t)b*256 + tc*CHUNK + tt2)*256 + d*128 + cc*4)) = v;
        }
        asm volatile("s_waitcnt lgkmcnt(0)" ::: "memory");
        __builtin_amdgcn_s_barrier();
        __builtin_amdgcn_sched_barrier(0);
      }
    }
  } else if (wg < 38) {
    // ======================= GX role =======================
    const int g  = wg - 6;
    const int lg = 1 + (g >> 4);
    const int cinf = (lg - 1) * 2;
    unsigned long long* gdst = (unsigned long long*)((lg == 1) ? gi1 : gi2);
    unsigned* fg = flags + 8 + (lg - 1)*32;
    _Float16* XL = (_Float16*)LDSU;

    for (int rep = 0; rep < 2; ++rep) {
      const int tc = (g & 15) + rep*16;
      const int t0 = tc * CHUNK;
      if (tid == 0) {
        while (__hip_atomic_load(flags + cinf, __ATOMIC_RELAXED,
                                 __HIP_MEMORY_SCOPE_AGENT) <= (unsigned)tc)
          __builtin_amdgcn_s_sleep(8);
        while (__hip_atomic_load(flags + cinf + 1, __ATOMIC_RELAXED,
                                 __HIP_MEMORY_SCOPE_AGENT) <= (unsigned)tc)
          __builtin_amdgcn_s_sleep(8);
        __builtin_amdgcn_fence(__ATOMIC_ACQUIRE, "agent");
      }
      __syncthreads();
      #pragma unroll
      for (int r = 0; r < 8; ++r) {
        int u = r*512 + tid;
        int cell = u >> 11, rem = u & 2047;
        int tt = rem >> 8, b = (rem >> 5) & 7, p = rem & 31;
        unsigned long long v = __hip_atomic_load(
            Hbuf + (((size_t)(cinf + cell)) << 16)
                 + (size_t)(t0 + tt)*256 + b*32 + p,
            __ATOMIC_RELAXED, __HIP_MEMORY_SCOPE_AGENT);
        int byte = (tt*4096 + b*512 + cell*256 + p*8) ^ ((b & 7) << 4);
        *(unsigned long long*)((char*)XL + byte) = v;
      }
      __syncthreads();

      f32x4 acc[2][3][4];
      #pragma unroll
      for (int c2 = 0; c2 < 2; ++c2)
        #pragma unroll
        for (int nt = 0; nt < 3; ++nt)
          #pragma unroll
          for (int mt = 0; mt < 4; ++mt) acc[c2][nt][mt] = (f32x4){0,0,0,0};

      for (int ks = 0; ks < 8; ++ks) {
        f16x8 a[4];
        #pragma unroll
        for (int mt = 0; mt < 4; ++mt) {
          int byte = ((mt*2 + (lo >> 3))*4096 + (lo & 7)*512 + 64*ks + 16*hi)
                     ^ ((lo & 7) << 4);
          a[mt] = *(const f16x8*)((const char*)XL + byte);
        }
        #pragma unroll
        for (int c2 = 0; c2 < 2; ++c2) {
          const size_t wb = (size_t)(2*lg + c2 - 2) * 384;
          #pragma unroll
          for (int nt = 0; nt < 3; ++nt) {
            f16x8 bw = *(const f16x8*)(Wx + (wb + 16*(w + 8*nt) + lo)*256
                                          + 32*ks + 8*hi);
            #pragma unroll
            for (int mt = 0; mt < 4; ++mt)
              acc[c2][nt][mt] = MFMA16(a[mt], bw, acc[c2][nt][mt]);
          }
        }
      }
      #pragma unroll
      for (int c2 = 0; c2 < 2; ++c2) {
        const int c = 2*lg + c2;
        #pragma unroll
        for (int nt = 0; nt < 3; ++nt) {
          int o = 16*(w + 8*nt) + lo;
          float badd = bih[(size_t)c*384 + o]
                     + ((o < 256) ? bhh[(size_t)c*384 + o] : 0.f);
          #pragma unroll
          for (int mt = 0; mt < 4; ++mt) {
            f32x4 v = acc[c2][nt][mt];
            v[0] += badd; v[1] += badd; v[2] += badd; v[3] += badd;
            int t = t0 + mt*2 + (hi >> 1), b0i = 4*(hi & 1);
            size_t ix = (size_t)t*3072 + (size_t)(c2*384 + o)*4 + (b0i >> 1);
            __hip_atomic_store(gdst + ix,     ((unsigned long long*)&v)[0],
                               __ATOMIC_RELAXED, __HIP_MEMORY_SCOPE_AGENT);
            __hip_atomic_store(gdst + ix + 1, ((unsigned long long*)&v)[1],
                               __ATOMIC_RELAXED, __HIP_MEMORY_SCOPE_AGENT);
          }
        }
      }
      asm volatile("s_waitcnt vmcnt(0)" ::: "memory");
      __syncthreads();
      if (tid == 0)
        __hip_atomic_store(fg + tc, 1u,
                           __ATOMIC_RELEASE, __HIP_MEMORY_SCOPE_AGENT);
      __syncthreads();
    }
  } else if (wg < 166) {
    // ======================= ATTN role =======================
    float* u2   = (float*)LDSU;                 // [2][4][256]
    float* sc2  = (float*)(LDSU + 8192);        // [2][4][256]
    float* vl   = (float*)(LDSU + 16384);       // [128]
    float* red2 = (float*)(LDSU + 16896);       // [2][4]
    const int side = tid >> 8, t2 = tid & 255;
    float* uu = u2  + side*1024;
    float* ss = sc2 + side*1024;
    float* rr = red2 + side*4;

    for (int rnd = 0; rnd < 2; ++rnd) {
      const int inst = rnd*256 + (wg - 38)*2 + side;
      const int b = inst & 7, q0 = (inst >> 3) << 2;
      if (tid < 128) vl[tid] = vw[tid];
      for (int k = t2; k < 512; k += 256) {
        int j = k >> 7, h = k & 127;
        uu[j*256 + h] = pbar[(((size_t)(q0+j))*8 + b)*128 + h];
      }
      __syncthreads();
      float s[4] = {0,0,0,0};
      for (int h = 0; h < 128; ++h) {
        float pk = prepT[((size_t)b*128 + h)*256 + t2];
        float vh = vl[h];
        #pragma unroll
        for (int j = 0; j < 4; ++j) {
          float e = __expf(2.f*(uu[j*256 + h] + pk));
          float tq = __builtin_amdgcn_rcpf(e + 1.f);
          s[j] = fmaf(vh, fmaf(-2.f, tq, 1.f), s[j]);
        }
      }
      #pragma unroll
      for (int j = 0; j < 4; ++j) {
        float v = s[j];
        #pragma unroll
        for (int off = 32; off > 0; off >>= 1) v = fmaxf(v, __shfl_xor(v, off));
        if ((t2 & 63) == 0) rr[t2 >> 6] = v;
        __syncthreads();
        float m = fmaxf(fmaxf(rr[0], rr[1]), fmaxf(rr[2], rr[3]));
        __syncthreads();
        float e = __expf(s[j] - m);
        v = e;
        #pragma unroll
        for (int off = 32; off > 0; off >>= 1) v += __shfl_xor(v, off);
        if ((t2 & 63) == 0) rr[t2 >> 6] = v;
        __syncthreads();
        float sum = rr[0] + rr[1] + rr[2] + rr[3];
        __syncthreads();
        ss[j*256 + t2] = e * __builtin_amdgcn_rcpf(sum);
      }
      __syncthreads();
      {
        int h = t2 & 127, jj = t2 >> 7;
        float c0 = 0.f, c1 = 0.f;
        for (int k = 0; k < 256; ++k) {
          float p = pbar[((size_t)k*8 + b)*128 + h];
          c0 += ss[jj*256 + k]     * p;
          c1 += ss[(jj+2)*256 + k] * p;
        }
        uu[jj*256 + 128 + h]     = c0;
        uu[(jj+2)*256 + 128 + h] = c1;
      }
      __syncthreads();
      {
        float gg[4] = {0,0,0,0};
        for (int dd = 0; dd < 256; ++dd) {
          float wv = gwT[(size_t)dd*256 + t2];
          #pragma unroll
          for (int j = 0; j < 4; ++j) gg[j] += uu[j*256 + dd] * wv;
        }
        #pragma unroll
        for (int j = 0; j < 4; ++j) {
          float ue = uu[j*256 + t2];
          ug[(((size_t)(q0+j))*8 + b)*256 + t2] = ue * fsig(gg[j]);
        }
      }
      asm volatile("s_waitcnt vmcnt(0)" ::: "memory");
      __syncthreads();
      if (t2 == 0)   // tid==0 (side 0) and tid==256 (side 1)
        __hip_atomic_fetch_add(flags + 104 + (inst >> 3), 1u,
                               __ATOMIC_RELEASE, __HIP_MEMORY_SCOPE_AGENT);
      __syncthreads();
    }
  } else {
    // ======================= GI0 role =======================
    const int tc = wg - 166;
    float* ul = (float*)LDSU;                   // [2][8][256]
    const int side = tid >> 8, t2 = tid & 255;
    float* us = ul + side*2048;
    if (tid == 0) {
      while (__hip_atomic_load(flags + 104 + 2*tc, __ATOMIC_RELAXED,
                               __HIP_MEMORY_SCOPE_AGENT) < 8u)
        __builtin_amdgcn_s_sleep(4);
      while (__hip_atomic_load(flags + 104 + 2*tc + 1, __ATOMIC_RELAXED,
                               __HIP_MEMORY_SCOPE_AGENT) < 8u)
        __builtin_amdgcn_s_sleep(4);
      __builtin_amdgcn_fence(__ATOMIC_ACQUIRE, "agent");
    }
    __syncthreads();
    for (int tp = 0; tp < 4; ++tp) {
      const int t = tc*8 + tp*2 + side;
      for (int k = t2; k < 2048; k += 256)
        us[(k >> 8)*256 + (k & 255)] = ug[(size_t)t*2048 + k];
      __syncthreads();
      float acc[3][8];
      #pragma unroll
      for (int a = 0; a < 3; ++a)
        #pragma unroll
        for (int r = 0; r < 8; ++r) acc[a][r] = 0.f;
      for (int i = 0; i < 256; ++i) {
        float w0 = Wih0T[(size_t)i*768 + t2];
        float w1 = Wih0T[(size_t)i*768 + 256 + t2];
        float w2 = Wih0T[(size_t)i*768 + 512 + t2];
        #pragma unroll
        for (int r = 0; r < 8; ++r) {
          float uv = us[r*256 + i];
          acc[0][r] += uv*w0; acc[1][r] += uv*w1; acc[2][r] += uv*w2;
        }
      }
      #pragma unroll
      for (int a = 0; a < 3; ++a) {
        int o = a*256 + t2;
        int og = (o >= 384) ? (o - 384) : o;       // gate-local (r10 lesson)
        float ba = bih[o] + ((og < 256) ? bhh[o] : 0.f);
        f32x4 v0 = {acc[a][0]+ba, acc[a][1]+ba, acc[a][2]+ba, acc[a][3]+ba};
        f32x4 v1 = {acc[a][4]+ba, acc[a][5]+ba, acc[a][6]+ba, acc[a][7]+ba};
        *(f32x4*)(gi0 + (size_t)t*6144 + o*8)     = v0;
        *(f32x4*)(gi0 + (size_t)t*6144 + o*8 + 4) = v1;
      }
      __syncthreads();
    }
    asm volatile("s_waitcnt vmcnt(0)" ::: "memory");
    __syncthreads();
    if (tid == 0)
      __hip_atomic_store(flags + 72 + tc, 1u,
                         __ATOMIC_RELEASE, __HIP_MEMORY_SCOPE_AGENT);
  }
}

extern "C" void kernel_launch(void* const* d_in, const int* in_sizes, int n_in,
                              void* d_out, int out_size, void* d_ws, size_t ws_size,
                              hipStream_t stream) {
  (void)in_sizes; (void)n_in; (void)out_size; (void)ws_size;
  const float* P     = (const float*)d_in[0];
  const float* vw    = (const float*)d_in[2];
  const float* WvP   = (const float*)d_in[3];
  const float* WvPb  = (const float*)d_in[4];
  const float* gatew = (const float*)d_in[5];
  const float* Wih   = (const float*)d_in[6];
  const float* Whh   = (const float*)d_in[7];
  const float* bih   = (const float*)d_in[8];
  const float* bhh   = (const float*)d_in[9];
  float* out = (float*)d_out;

  char* wsp = (char*)d_ws;
  size_t off = 0;
  auto alloc = [&](size_t nbytes) -> void* {
    void* p = wsp + off;
    off += (nbytes + 255) & ~(size_t)255;
    return p;
  };
  float*    prepT = (float*)   alloc((size_t)8*128*256*4);
  float*    pbar  = (float*)   alloc((size_t)256*8*128*4);
  float*    ug    = (float*)   alloc((size_t)256*8*256*4);
  float*    gi0   = (float*)   alloc((size_t)256*768*8*4);   // [t][o][b]
  float*    gi1   = (float*)   alloc((size_t)256*768*8*4);
  float*    gi2   = (float*)   alloc((size_t)256*768*8*4);
  unsigned long long* Hbuf = (unsigned long long*)alloc((size_t)4*256*8*32*8);
  _Float16* Wx    = (_Float16*)alloc((size_t)4*384*256*2);
  _Float16* Wh    = (_Float16*)alloc((size_t)6*384*128*2);
  float*    WvPT  = (float*)   alloc((size_t)256*128*4);
  float*    WvPbT = (float*)   alloc((size_t)256*128*4);
  float*    gwT   = (float*)   alloc((size_t)256*256*4);
  float*    Wih0T = (float*)   alloc((size_t)256*768*4);
  unsigned* flags = (unsigned*)alloc((size_t)256*4);

  hipLaunchKernelGGL(k_prep, dim3(256), dim3(256), 0, stream,
                     WvP, WvPb, gatew, Wih, Whh, WvPT, WvPbT, gwT, Wih0T, Wx, Wh,
                     flags);
  hipLaunchKernelGGL(k_prep_pbar, dim3(512), dim3(256), 0, stream,
                     P, WvPT, WvPbT, prepT, pbar);
  hipLaunchKernelGGL(k_fused, dim3(198), dim3(512), 0, stream,
                     Wx, Wh, prepT, pbar, vw, gwT, Wih0T, ug,
                     gi0, gi1, gi2, bih, bhh, Hbuf, out, flags);
}

// Round 16
// 454.634 us; speedup vs baseline: 1.1066x; 1.1066x over previous
//
#include <hip/hip_runtime.h>
#include <hip/hip_bf16.h>

// Problem dims (fixed): T=256, B=8, H=128, IN=256
#define T_LEN 256
#define CHUNK 8
#define NCHUNK (T_LEN / CHUNK)

typedef _Float16 f16x8 __attribute__((ext_vector_type(8)));
typedef float f32x4 __attribute__((ext_vector_type(4)));

__device__ __forceinline__ float fsig(float x) {
  return __builtin_amdgcn_rcpf(1.f + __expf(-x));
}
__device__ __forceinline__ float ftanhf(float x) {
  return fmaf(-2.f, __builtin_amdgcn_rcpf(1.f + __expf(2.f * x)), 1.f);
}

#define MFMA16(a,b,c) __builtin_amdgcn_mfma_f32_16x16x32_f16(a, b, c, 0, 0, 0)
#define PIN(x) asm volatile("" : "+v"(*reinterpret_cast<f32x4*>(&(x))))

// ---------------- weight reformat (+ flag zero) ----------------
__global__ void k_prep(const float* __restrict__ WvP, const float* __restrict__ WvPb,
                       const float* __restrict__ gatew,
                       const float* __restrict__ Wih, const float* __restrict__ Whh,
                       float* __restrict__ WvPT, float* __restrict__ WvPbT,
                       float* __restrict__ gwT, float* __restrict__ Wih0T,
                       _Float16* __restrict__ Wx, _Float16* __restrict__ Wh,
                       unsigned* __restrict__ flags) {
  int n = blockIdx.x*blockDim.x + threadIdx.x;
  int NT = gridDim.x*blockDim.x;
  if (n < 128) flags[n] = 0u;
  for (int k = n; k < 256*128; k += NT) {
    int i = k >> 7, h = k & 127;
    WvPT[k]  = WvP[h*256 + i];
    WvPbT[k] = WvPb[h*256 + i];
  }
  for (int k = n; k < 256*256; k += NT) {
    int dd = k >> 8, e = k & 255;
    gwT[k] = gatew[e*256 + dd];
  }
  for (int k = n; k < 256*768; k += NT) {
    int i = k / 768, doo = k % 768;
    Wih0T[k] = Wih[(size_t)doo*256 + i];
  }
  for (int k = n; k < 6*384*128; k += NT) {
    Wh[k] = (_Float16)Whh[k];           // flat [c][o][128]
  }
  for (int k = n; k < 4*384*256; k += NT) {
    Wx[k] = (_Float16)Wih[(size_t)2*384*256 + k];  // cells 2..5
  }
}

// ---------------- prep/pbar projections ----------------
__global__ __launch_bounds__(256) void k_prep_pbar(
    const float* __restrict__ P, const float* __restrict__ WvPT,
    const float* __restrict__ WvPbT, float* __restrict__ prepT,
    float* __restrict__ pbar) {
  __shared__ float Pl[4*256];
  int R0 = blockIdx.x * 4, tid = threadIdx.x;
  for (int k = tid; k < 1024; k += 256) Pl[k] = P[(size_t)R0*256 + k];
  __syncthreads();
  int h = tid & 127;
  const float* Wt = (tid < 128) ? WvPT : WvPbT;
  float acc[4] = {0,0,0,0};
  for (int i = 0; i < 256; ++i) {
    float w = Wt[i*128 + h];
    acc[0] += Pl[i]*w; acc[1] += Pl[256+i]*w;
    acc[2] += Pl[512+i]*w; acc[3] += Pl[768+i]*w;
  }
  #pragma unroll
  for (int r = 0; r < 4; ++r) {
    int R = R0 + r, t = R >> 3, b = R & 7;
    if (tid < 128) prepT[((size_t)b*128 + h)*256 + t] = acc[r];
    else           pbar[(size_t)R*128 + h] = acc[r];
  }
}

// ---------------- fused attention + gate (division-free) ----------------
__global__ __launch_bounds__(256) void k_attn(
    const float* __restrict__ prepT, const float* __restrict__ pbar,
    const float* __restrict__ vw, const float* __restrict__ gwT,
    float* __restrict__ ug) {
  int b = blockIdx.x & 7, q0 = (blockIdx.x >> 3) * 4;
  int tid = threadIdx.x;
  __shared__ float u[4][256];
  __shared__ float vl[128];
  __shared__ float sc[4][256];
  __shared__ float red[4];
  if (tid < 128) vl[tid] = vw[tid];
  for (int k = tid; k < 512; k += 256) {
    int j = k >> 7, h = k & 127;
    u[j][h] = pbar[(((size_t)(q0+j))*8 + b)*128 + h];
  }
  __syncthreads();
  float s[4] = {0,0,0,0};
  for (int h = 0; h < 128; ++h) {
    float pk = prepT[((size_t)b*128 + h)*256 + tid];
    float vh = vl[h];
    #pragma unroll
    for (int j = 0; j < 4; ++j) {
      float e = __expf(2.f*(u[j][h] + pk));
      float t = __builtin_amdgcn_rcpf(e + 1.f);      // tanh = 1-2t
      s[j] = fmaf(vh, fmaf(-2.f, t, 1.f), s[j]);
    }
  }
  #pragma unroll
  for (int j = 0; j < 4; ++j) {
    float v = s[j];
    #pragma unroll
    for (int off = 32; off > 0; off >>= 1) v = fmaxf(v, __shfl_xor(v, off));
    if ((tid & 63) == 0) red[tid >> 6] = v;
    __syncthreads();
    float m = fmaxf(fmaxf(red[0], red[1]), fmaxf(red[2], red[3]));
    __syncthreads();
    float e = __expf(s[j] - m);
    v = e;
    #pragma unroll
    for (int off = 32; off > 0; off >>= 1) v += __shfl_xor(v, off);
    if ((tid & 63) == 0) red[tid >> 6] = v;
    __syncthreads();
    float sum = red[0] + red[1] + red[2] + red[3];
    __syncthreads();
    sc[j][tid] = e * __builtin_amdgcn_rcpf(sum);
  }
  __syncthreads();
  {
    int h = tid & 127, jj = tid >> 7;
    float c0 = 0.f, c1 = 0.f;
    for (int k = 0; k < 256; ++k) {
      float p = pbar[((size_t)k*8 + b)*128 + h];
      c0 += sc[jj][k]   * p;
      c1 += sc[jj+2][k] * p;
    }
    u[jj][128+h]   = c0;
    u[jj+2][128+h] = c1;
  }
  __syncthreads();
  {
    float gg[4] = {0,0,0,0};
    for (int dd = 0; dd < 256; ++dd) {
      float w = gwT[(size_t)dd*256 + tid];
      #pragma unroll
      for (int j = 0; j < 4; ++j) gg[j] += u[j][dd] * w;
    }
    #pragma unroll
    for (int j = 0; j < 4; ++j) {
      float ue = u[j][tid];
      ug[(((size_t)(q0+j))*8 + b)*256 + tid] = ue * fsig(gg[j]);
    }
  }
}

// ---------------- gi0 = ug @ Wih0^T + bih (+bhh for r,z) : [t][768][8] -------
__global__ __launch_bounds__(256) void k_gi0(
    const float* __restrict__ ug, const float* __restrict__ Wih0T,
    const float* __restrict__ bih, const float* __restrict__ bhh,
    float* __restrict__ gi0) {
  __shared__ float ul[8][256];
  __shared__ float st[768*8];
  int t = blockIdx.x, tid = threadIdx.x;
  for (int k = tid; k < 2048; k += 256) ul[k >> 8][k & 255] = ug[(size_t)t*2048 + k];
  __syncthreads();
  float acc[3][8];
  #pragma unroll
  for (int a = 0; a < 3; ++a)
    #pragma unroll
    for (int r = 0; r < 8; ++r) acc[a][r] = 0.f;
  for (int i = 0; i < 256; ++i) {
    float w0 = Wih0T[(size_t)i*768 + tid];
    float w1 = Wih0T[(size_t)i*768 + 256 + tid];
    float w2 = Wih0T[(size_t)i*768 + 512 + tid];
    #pragma unroll
    for (int r = 0; r < 8; ++r) {
      float uu = ul[r][i];
      acc[0][r] += uu*w0; acc[1][r] += uu*w1; acc[2][r] += uu*w2;
    }
  }
  #pragma unroll
  for (int a = 0; a < 3; ++a) {
    int o = a*256 + tid;
    int og = (o >= 384) ? (o - 384) : o;               // gate-local (r10 fix)
    float ba = bih[o] + ((og < 256) ? bhh[o] : 0.f);   // fold bhh for r,z
    #pragma unroll
    for (int r = 0; r < 8; ++r) st[o*8 + r] = acc[a][r] + ba;
  }
  __syncthreads();
  #pragma unroll
  for (int j = 0; j < 6; ++j) {
    int idx = j*256 + tid;
    ((f32x4*)gi0)[(size_t)t*1536 + idx] = ((const f32x4*)st)[idx];
  }
}

// ---------------- k_gru16: r13 structure, slimmed serial chain ---------------
// wg 0..5 : CELL. Changes vs r13: (1) gate MFMA chains split 2+2 (depth 2,
//           -2 MFMA latencies on serial path); (2) l==2 stores out DIRECTLY
//           per step (fire-and-forget; no SL stage, no chunk flush/drain);
//           (3) l==0 prefetch continuous across chunks (no poll, no bubble).
// wg 6..37: GX (r12-proven chunk GEMM, unchanged). Heater removed (null).
__global__ __launch_bounds__(512, 1) void k_gru16(
    const _Float16* __restrict__ Wx, const _Float16* __restrict__ Wh,
    const float* __restrict__ gi0, float* __restrict__ gi1,
    float* __restrict__ gi2, const float* __restrict__ bih,
    const float* __restrict__ bhh, unsigned long long* Hbuf,
    float* __restrict__ out, unsigned* flags)
{
  const int wg = blockIdx.x;
  const int tid = threadIdx.x;
  const int w = tid >> 6, lane = tid & 63;
  const int lo = lane & 15, hi = lane >> 4;

  __shared__ char LDSU[36864];   // cell: SL 32K + hlds 4K ; gx: XL 32K

  if (wg < 6) {
    // ======================= CELL role =======================
    const int c = wg, l = c >> 1, d = c & 1;
    _Float16* hlds = (_Float16*)(LDSU + 32768);   // [2][8*128]
    char* SL = LDSU;

    { f16x8 z = {0,0,0,0,0,0,0,0};
      for (int p = tid; p < 256; p += 512) ((f16x8*)hlds)[p] = z; }

    f16x8 bh[3][4];
    #pragma unroll
    for (int nt = 0; nt < 3; ++nt) {
      int o = 16*(w + 8*nt) + lo;
      #pragma unroll
      for (int ks = 0; ks < 4; ++ks)
        bh[nt][ks] = *(const f16x8*)(Wh + ((size_t)c*384 + o)*128 + 32*ks + 8*hi);
    }
    #pragma unroll
    for (int nt = 0; nt < 3; ++nt)
      #pragma unroll
      for (int ks = 0; ks < 4; ++ks)
        PIN(bh[nt][ks]);

    const int hidx = 16*w + lo;
    const float b_hn = bhh[(size_t)c*384 + 256 + hidx];
    const int b0 = 4*(hi & 1);

    const float* gplain = gi0 + (size_t)d*384*8;              // l==0 path
    const unsigned long long* gatom =                          // l>0 path
        (const unsigned long long*)((l == 1) ? gi1 : gi2) + (size_t)(d*384)*4;
    unsigned* fg = flags + 8 + (l > 0 ? (l-1)*32 : 0);

    f32x4 gA0,gA1,gA2, gB0,gB1,gB2;
    auto LD = [&](int t, f32x4& x0, f32x4& x1, f32x4& x2) {
      if (l == 0) {
        const float* g = gplain + (size_t)t*768*8;
        x0 = *(const f32x4*)(g + (size_t)hidx*8 + b0);
        x1 = *(const f32x4*)(g + ((size_t)128 + hidx)*8 + b0);
        x2 = *(const f32x4*)(g + ((size_t)256 + hidx)*8 + b0);
      } else {
        const unsigned long long* g = gatom + (size_t)t*3072 + (b0 >> 1);
        #pragma unroll
        for (int a = 0; a < 3; ++a) {
          size_t ix = (size_t)(a*128 + hidx)*4;
          unsigned long long u0 = __hip_atomic_load(g + ix,
              __ATOMIC_RELAXED, __HIP_MEMORY_SCOPE_AGENT);
          unsigned long long u1 = __hip_atomic_load(g + ix + 1,
              __ATOMIC_RELAXED, __HIP_MEMORY_SCOPE_AGENT);
          f32x4 v;
          ((unsigned long long*)&v)[0] = u0;
          ((unsigned long long*)&v)[1] = u1;
          if (a == 0) x0 = v; else if (a == 1) x1 = v; else x2 = v;
        }
      }
    };

    float hp[4] = {0,0,0,0};
    __syncthreads();

    if (l == 0) {   // continuous prefetch; gi0 fully materialized already
      LD(0, gA0, gA1, gA2);
      LD(1, gB0, gB1, gB2);
    }

    for (int tc = 0; tc < NCHUNK; ++tc) {
      if (l > 0) {
        if (tid == 0) {
          while (__hip_atomic_load(fg + tc, __ATOMIC_RELAXED,
                                   __HIP_MEMORY_SCOPE_AGENT) == 0u)
            __builtin_amdgcn_s_sleep(2);
          __builtin_amdgcn_fence(__ATOMIC_ACQUIRE, "agent");
        }
        __syncthreads();
        LD(tc*CHUNK,     gA0, gA1, gA2);
        LD(tc*CHUNK + 1, gB0, gB1, gB2);
      }

      #pragma unroll
      for (int tt = 0; tt < CHUNK; ++tt) {
        const int t = tc*CHUNK + tt;
        f32x4 ax0, ax1, ax2;
        const bool more = (tt + 2 < CHUNK) || (l == 0 && t + 2 < T_LEN);
        if (!(tt & 1)) {
          ax0 = gA0; ax1 = gA1; ax2 = gA2;
          if (more) LD(t + 2, gA0, gA1, gA2);
        } else {
          ax0 = gB0; ax1 = gB1; ax2 = gB2;
          if (more) LD(t + 2, gB0, gB1, gB2);
        }
        // h-part MFMAs: 2+2 split accumulators (serial depth 2, not 4)
        f32x4 ah0 = {0,0,0,0}, ah1 = {0,0,0,0}, ah2 = {0,0,0,0};
        f32x4 bh0 = {0,0,0,0}, bh1 = {0,0,0,0}, bh2 = {0,0,0,0};
        {
          const char* hb = (const char*)hlds + (t & 1)*2048;
          f16x8 a[4];
          #pragma unroll
          for (int ks = 0; ks < 4; ++ks) {
            int byte = ((lo & 7)*256 + (32*ks + 8*hi)*2) ^ ((lo & 7) << 4);
            a[ks] = *(const f16x8*)(hb + byte);
          }
          ah0 = MFMA16(a[0], bh[0][0], ah0);
          ah1 = MFMA16(a[0], bh[1][0], ah1);
          ah2 = MFMA16(a[0], bh[2][0], ah2);
          bh0 = MFMA16(a[2], bh[0][2], bh0);
          bh1 = MFMA16(a[2], bh[1][2], bh1);
          bh2 = MFMA16(a[2], bh[2][2], bh2);
          ah0 = MFMA16(a[1], bh[0][1], ah0);
          ah1 = MFMA16(a[1], bh[1][1], ah1);
          ah2 = MFMA16(a[1], bh[2][1], ah2);
          bh0 = MFMA16(a[3], bh[0][3], bh0);
          bh1 = MFMA16(a[3], bh[1][3], bh1);
          bh2 = MFMA16(a[3], bh[2][3], bh2);
          ah0 += bh0; ah1 += bh1; ah2 += bh2;
        }
        // slim combine
        float hn[4];
        #pragma unroll
        for (int q = 0; q < 4; ++q) {
          float r  = fsig(ax0[q] + ah0[q]);
          float z  = fsig(ax1[q] + ah1[q]);
          float nn = ftanhf(fmaf(r, ah2[q] + b_hn, ax2[q]));
          hn[q] = fmaf(z, hp[q] - nn, nn);
          hp[q] = hn[q];
        }
        // write h (+ stage l<2 / direct-store l==2)
        if (lane < 32) {
          char* hb2 = (char*)hlds + ((t + 1) & 1)*2048;
          #pragma unroll
          for (int q = 0; q < 4; ++q) {
            int b = 4*hi + q;
            int byte = (b*256 + hidx*2) ^ (b << 4);
            *(_Float16*)(hb2 + byte) = (_Float16)hn[q];
            if (l < 2) *(_Float16*)(SL + (tt*8 + b)*256 + hidx*2) = (_Float16)hn[q];
            else       out[((size_t)b*256 + t)*256 + d*128 + hidx] = hn[q];
          }
        }
        asm volatile("s_waitcnt lgkmcnt(0)" ::: "memory");
        __builtin_amdgcn_s_barrier();
        __builtin_amdgcn_sched_barrier(0);
      }

      // chunk flush (producers only; l==2 already stored out directly)
      if (l < 2) {
        #pragma unroll
        for (int i = 0; i < 4; ++i) {
          int u = i*512 + tid;                  // 2048 8B units
          int tt2 = u >> 8, b = (u >> 5) & 7, pu = u & 31;
          unsigned long long v = *(const unsigned long long*)
              (SL + (tt2*8 + b)*256 + pu*8);
          __hip_atomic_store(Hbuf + (((size_t)c) << 16)
                                  + (size_t)(tc*CHUNK + tt2)*256 + b*32 + pu,
                             v, __ATOMIC_RELAXED, __HIP_MEMORY_SCOPE_AGENT);
        }
        asm volatile("s_waitcnt vmcnt(0)" ::: "memory");
        __syncthreads();
        if (tid == 0)
          __hip_atomic_store(flags + c, (unsigned)(tc + 1),
                             __ATOMIC_RELEASE, __HIP_MEMORY_SCOPE_AGENT);
      }
    }
  } else {
    // ======================= GX role =======================
    const int g  = wg - 6;
    const int lg = 1 + (g >> 4);          // target layer 1 or 2
    const int cinf = (lg - 1) * 2;        // source cells
    unsigned long long* gdst = (unsigned long long*)((lg == 1) ? gi1 : gi2);
    unsigned* fg = flags + 8 + (lg - 1)*32;
    _Float16* XL = (_Float16*)LDSU;

    for (int rep = 0; rep < 2; ++rep) {
      const int tc = (g & 15) + rep*16;
      const int t0 = tc * CHUNK;
      if (tid == 0) {
        while (__hip_atomic_load(flags + cinf, __ATOMIC_RELAXED,
                                 __HIP_MEMORY_SCOPE_AGENT) <= (unsigned)tc)
          __builtin_amdgcn_s_sleep(8);
        while (__hip_atomic_load(flags + cinf + 1, __ATOMIC_RELAXED,
                                 __HIP_MEMORY_SCOPE_AGENT) <= (unsigned)tc)
          __builtin_amdgcn_s_sleep(8);
        __builtin_amdgcn_fence(__ATOMIC_ACQUIRE, "agent");
      }
      __syncthreads();
      #pragma unroll
      for (int r = 0; r < 8; ++r) {
        int u = r*512 + tid;                  // 4096 8B units
        int cell = u >> 11, rem = u & 2047;
        int tt = rem >> 8, b = (rem >> 5) & 7, p = rem & 31;
        unsigned long long v = __hip_atomic_load(
            Hbuf + (((size_t)(cinf + cell)) << 16)
                 + (size_t)(t0 + tt)*256 + b*32 + p,
            __ATOMIC_RELAXED, __HIP_MEMORY_SCOPE_AGENT);
        int byte = (tt*4096 + b*512 + cell*256 + p*8) ^ ((b & 7) << 4);
        *(unsigned long long*)((char*)XL + byte) = v;
      }
      __syncthreads();

      f32x4 acc[2][3][4];
      #pragma unroll
      for (int c2 = 0; c2 < 2; ++c2)
        #pragma unroll
        for (int nt = 0; nt < 3; ++nt)
          #pragma unroll
          for (int mt = 0; mt < 4; ++mt) acc[c2][nt][mt] = (f32x4){0,0,0,0};

      for (int ks = 0; ks < 8; ++ks) {
        f16x8 a[4];
        #pragma unroll
        for (int mt = 0; mt < 4; ++mt) {
          int byte = ((mt*2 + (lo >> 3))*4096 + (lo & 7)*512 + 64*ks + 16*hi)
                     ^ ((lo & 7) << 4);
          a[mt] = *(const f16x8*)((const char*)XL + byte);
        }
        #pragma unroll
        for (int c2 = 0; c2 < 2; ++c2) {
          const size_t wb = (size_t)(2*lg + c2 - 2) * 384;
          #pragma unroll
          for (int nt = 0; nt < 3; ++nt) {
            f16x8 bw = *(const f16x8*)(Wx + (wb + 16*(w + 8*nt) + lo)*256
                                          + 32*ks + 8*hi);
            #pragma unroll
            for (int mt = 0; mt < 4; ++mt)
              acc[c2][nt][mt] = MFMA16(a[mt], bw, acc[c2][nt][mt]);
          }
        }
      }
      // bias epilogue + gi stores
      #pragma unroll
      for (int c2 = 0; c2 < 2; ++c2) {
        const int c = 2*lg + c2;
        #pragma unroll
        for (int nt = 0; nt < 3; ++nt) {
          int o = 16*(w + 8*nt) + lo;           // 0..383 gate-local
          float badd = bih[(size_t)c*384 + o]
                     + ((o < 256) ? bhh[(size_t)c*384 + o] : 0.f);
          #pragma unroll
          for (int mt = 0; mt < 4; ++mt) {
            f32x4 v = acc[c2][nt][mt];
            v[0] += badd; v[1] += badd; v[2] += badd; v[3] += badd;
            int t = t0 + mt*2 + (hi >> 1), b0i = 4*(hi & 1);
            size_t ix = (size_t)t*3072 + (size_t)(c2*384 + o)*4 + (b0i >> 1);
            __hip_atomic_store(gdst + ix,     ((unsigned long long*)&v)[0],
                               __ATOMIC_RELAXED, __HIP_MEMORY_SCOPE_AGENT);
            __hip_atomic_store(gdst + ix + 1, ((unsigned long long*)&v)[1],
                               __ATOMIC_RELAXED, __HIP_MEMORY_SCOPE_AGENT);
          }
        }
      }
      asm volatile("s_waitcnt vmcnt(0)" ::: "memory");
      __syncthreads();
      if (tid == 0)
        __hip_atomic_store(fg + tc, 1u,
                           __ATOMIC_RELEASE, __HIP_MEMORY_SCOPE_AGENT);
      __syncthreads();   // XL WAR before next rep
    }
  }
}

extern "C" void kernel_launch(void* const* d_in, const int* in_sizes, int n_in,
                              void* d_out, int out_size, void* d_ws, size_t ws_size,
                              hipStream_t stream) {
  (void)in_sizes; (void)n_in; (void)out_size; (void)ws_size;
  const float* P     = (const float*)d_in[0];
  const float* vw    = (const float*)d_in[2];
  const float* WvP   = (const float*)d_in[3];
  const float* WvPb  = (const float*)d_in[4];
  const float* gatew = (const float*)d_in[5];
  const float* Wih   = (const float*)d_in[6];
  const float* Whh   = (const float*)d_in[7];
  const float* bih   = (const float*)d_in[8];
  const float* bhh   = (const float*)d_in[9];
  float* out = (float*)d_out;

  char* wsp = (char*)d_ws;
  size_t off = 0;
  auto alloc = [&](size_t nbytes) -> void* {
    void* p = wsp + off;
    off += (nbytes + 255) & ~(size_t)255;
    return p;
  };
  float*    prepT = (float*)   alloc((size_t)8*128*256*4);
  float*    pbar  = (float*)   alloc((size_t)256*8*128*4);
  float*    ug    = (float*)   alloc((size_t)256*8*256*4);
  float*    gi0   = (float*)   alloc((size_t)256*768*8*4);   // [t][o][b]
  float*    gi1   = (float*)   alloc((size_t)256*768*8*4);
  float*    gi2   = (float*)   alloc((size_t)256*768*8*4);
  unsigned long long* Hbuf = (unsigned long long*)alloc((size_t)4*256*8*32*8);
  _Float16* Wx    = (_Float16*)alloc((size_t)4*384*256*2);
  _Float16* Wh    = (_Float16*)alloc((size_t)6*384*128*2);
  float*    WvPT  = (float*)   alloc((size_t)256*128*4);
  float*    WvPbT = (float*)   alloc((size_t)256*128*4);
  float*    gwT   = (float*)   alloc((size_t)256*256*4);
  float*    Wih0T = (float*)   alloc((size_t)256*768*4);
  unsigned* flags = (unsigned*)alloc((size_t)128*4);

  hipLaunchKernelGGL(k_prep, dim3(256), dim3(256), 0, stream,
                     WvP, WvPb, gatew, Wih, Whh, WvPT, WvPbT, gwT, Wih0T, Wx, Wh,
                     flags);
  hipLaunchKernelGGL(k_prep_pbar, dim3(512), dim3(256), 0, stream,
                     P, WvPT, WvPbT, prepT, pbar);
  hipLaunchKernelGGL(k_attn, dim3(512), dim3(256), 0, stream,
                     prepT, pbar, vw, gwT, ug);
  hipLaunchKernelGGL(k_gi0, dim3(256), dim3(256), 0, stream,
                     ug, Wih0T, bih, bhh, gi0);
  hipLaunchKernelGGL(k_gru16, dim3(38), dim3(512), 0, stream,
                     Wx, Wh, gi0, gi1, gi2, bih, bhh, Hbuf, out, flags);
}

// Round 17
// 453.081 us; speedup vs baseline: 1.1104x; 1.0034x over previous
//
#include <hip/hip_runtime.h>
#include <hip/hip_bf16.h>

// Problem dims (fixed): T=256, B=8, H=128, IN=256
#define T_LEN 256
#define CHUNK 8
#define NCHUNK (T_LEN / CHUNK)

typedef _Float16 f16x8 __attribute__((ext_vector_type(8)));
typedef float f32x4 __attribute__((ext_vector_type(4)));

__device__ __forceinline__ float fsig(float x) {
  return __builtin_amdgcn_rcpf(1.f + __expf(-x));
}
__device__ __forceinline__ float ftanhf(float x) {
  return fmaf(-2.f, __builtin_amdgcn_rcpf(1.f + __expf(2.f * x)), 1.f);
}

#define MFMA16(a,b,c) __builtin_amdgcn_mfma_f32_16x16x32_f16(a, b, c, 0, 0, 0)
#define PIN(x) asm volatile("" : "+v"(*reinterpret_cast<f32x4*>(&(x))))

// ---------------- weight reformat (+ flag zero) ----------------
__global__ void k_prep(const float* __restrict__ WvP, const float* __restrict__ WvPb,
                       const float* __restrict__ gatew,
                       const float* __restrict__ Wih, const float* __restrict__ Whh,
                       float* __restrict__ WvPT, float* __restrict__ WvPbT,
                       float* __restrict__ gwT, float* __restrict__ Wih0T,
                       _Float16* __restrict__ Wx, _Float16* __restrict__ Wh,
                       unsigned* __restrict__ flags) {
  int n = blockIdx.x*blockDim.x + threadIdx.x;
  int NT = gridDim.x*blockDim.x;
  if (n < 128) flags[n] = 0u;
  for (int k = n; k < 256*128; k += NT) {
    int i = k >> 7, h = k & 127;
    WvPT[k]  = WvP[h*256 + i];
    WvPbT[k] = WvPb[h*256 + i];
  }
  for (int k = n; k < 256*256; k += NT) {
    int dd = k >> 8, e = k & 255;
    gwT[k] = gatew[e*256 + dd];
  }
  for (int k = n; k < 256*768; k += NT) {
    int i = k / 768, doo = k % 768;
    Wih0T[k] = Wih[(size_t)doo*256 + i];
  }
  for (int k = n; k < 6*384*128; k += NT) {
    Wh[k] = (_Float16)Whh[k];           // flat [c][o][128]
  }
  for (int k = n; k < 4*384*256; k += NT) {
    Wx[k] = (_Float16)Wih[(size_t)2*384*256 + k];  // cells 2..5
  }
}

// ---------------- prep/pbar projections ----------------
__global__ __launch_bounds__(256) void k_prep_pbar(
    const float* __restrict__ P, const float* __restrict__ WvPT,
    const float* __restrict__ WvPbT, float* __restrict__ prepT,
    float* __restrict__ pbar) {
  __shared__ float Pl[4*256];
  int R0 = blockIdx.x * 4, tid = threadIdx.x;
  for (int k = tid; k < 1024; k += 256) Pl[k] = P[(size_t)R0*256 + k];
  __syncthreads();
  int h = tid & 127;
  const float* Wt = (tid < 128) ? WvPT : WvPbT;
  float acc[4] = {0,0,0,0};
  for (int i = 0; i < 256; ++i) {
    float w = Wt[i*128 + h];
    acc[0] += Pl[i]*w; acc[1] += Pl[256+i]*w;
    acc[2] += Pl[512+i]*w; acc[3] += Pl[768+i]*w;
  }
  #pragma unroll
  for (int r = 0; r < 4; ++r) {
    int R = R0 + r, t = R >> 3, b = R & 7;
    if (tid < 128) prepT[((size_t)b*128 + h)*256 + t] = acc[r];
    else           pbar[(size_t)R*128 + h] = acc[r];
  }
}

// ---------------- fused attention + gate (division-free) ----------------
__global__ __launch_bounds__(256) void k_attn(
    const float* __restrict__ prepT, const float* __restrict__ pbar,
    const float* __restrict__ vw, const float* __restrict__ gwT,
    float* __restrict__ ug) {
  int b = blockIdx.x & 7, q0 = (blockIdx.x >> 3) * 4;
  int tid = threadIdx.x;
  __shared__ float u[4][256];
  __shared__ float vl[128];
  __shared__ float sc[4][256];
  __shared__ float red[4];
  if (tid < 128) vl[tid] = vw[tid];
  for (int k = tid; k < 512; k += 256) {
    int j = k >> 7, h = k & 127;
    u[j][h] = pbar[(((size_t)(q0+j))*8 + b)*128 + h];
  }
  __syncthreads();
  float s[4] = {0,0,0,0};
  for (int h = 0; h < 128; ++h) {
    float pk = prepT[((size_t)b*128 + h)*256 + tid];
    float vh = vl[h];
    #pragma unroll
    for (int j = 0; j < 4; ++j) {
      float e = __expf(2.f*(u[j][h] + pk));
      float t = __builtin_amdgcn_rcpf(e + 1.f);      // tanh = 1-2t
      s[j] = fmaf(vh, fmaf(-2.f, t, 1.f), s[j]);
    }
  }
  #pragma unroll
  for (int j = 0; j < 4; ++j) {
    float v = s[j];
    #pragma unroll
    for (int off = 32; off > 0; off >>= 1) v = fmaxf(v, __shfl_xor(v, off));
    if ((tid & 63) == 0) red[tid >> 6] = v;
    __syncthreads();
    float m = fmaxf(fmaxf(red[0], red[1]), fmaxf(red[2], red[3]));
    __syncthreads();
    float e = __expf(s[j] - m);
    v = e;
    #pragma unroll
    for (int off = 32; off > 0; off >>= 1) v += __shfl_xor(v, off);
    if ((tid & 63) == 0) red[tid >> 6] = v;
    __syncthreads();
    float sum = red[0] + red[1] + red[2] + red[3];
    __syncthreads();
    sc[j][tid] = e * __builtin_amdgcn_rcpf(sum);
  }
  __syncthreads();
  {
    int h = tid & 127, jj = tid >> 7;
    float c0 = 0.f, c1 = 0.f;
    for (int k = 0; k < 256; ++k) {
      float p = pbar[((size_t)k*8 + b)*128 + h];
      c0 += sc[jj][k]   * p;
      c1 += sc[jj+2][k] * p;
    }
    u[jj][128+h]   = c0;
    u[jj+2][128+h] = c1;
  }
  __syncthreads();
  {
    float gg[4] = {0,0,0,0};
    for (int dd = 0; dd < 256; ++dd) {
      float w = gwT[(size_t)dd*256 + tid];
      #pragma unroll
      for (int j = 0; j < 4; ++j) gg[j] += u[j][dd] * w;
    }
    #pragma unroll
    for (int j = 0; j < 4; ++j) {
      float ue = u[j][tid];
      ug[(((size_t)(q0+j))*8 + b)*256 + tid] = ue * fsig(gg[j]);
    }
  }
}

// ---------------- gi0 = ug @ Wih0^T + bih (+bhh for r,z) : [t][768][8] -------
__global__ __launch_bounds__(256) void k_gi0(
    const float* __restrict__ ug, const float* __restrict__ Wih0T,
    const float* __restrict__ bih, const float* __restrict__ bhh,
    float* __restrict__ gi0) {
  __shared__ float ul[8][256];
  __shared__ float st[768*8];
  int t = blockIdx.x, tid = threadIdx.x;
  for (int k = tid; k < 2048; k += 256) ul[k >> 8][k & 255] = ug[(size_t)t*2048 + k];
  __syncthreads();
  float acc[3][8];
  #pragma unroll
  for (int a = 0; a < 3; ++a)
    #pragma unroll
    for (int r = 0; r < 8; ++r) acc[a][r] = 0.f;
  for (int i = 0; i < 256; ++i) {
    float w0 = Wih0T[(size_t)i*768 + tid];
    float w1 = Wih0T[(size_t)i*768 + 256 + tid];
    float w2 = Wih0T[(size_t)i*768 + 512 + tid];
    #pragma unroll
    for (int r = 0; r < 8; ++r) {
      float uu = ul[r][i];
      acc[0][r] += uu*w0; acc[1][r] += uu*w1; acc[2][r] += uu*w2;
    }
  }
  #pragma unroll
  for (int a = 0; a < 3; ++a) {
    int o = a*256 + tid;
    int og = (o >= 384) ? (o - 384) : o;               // gate-local (r10 fix)
    float ba = bih[o] + ((og < 256) ? bhh[o] : 0.f);   // fold bhh for r,z
    #pragma unroll
    for (int r = 0; r < 8; ++r) st[o*8 + r] = acc[a][r] + ba;
  }
  __syncthreads();
  #pragma unroll
  for (int j = 0; j < 6; ++j) {
    int idx = j*256 + tid;
    ((f32x4*)gi0)[(size_t)t*1536 + idx] = ((const f32x4*)st)[idx];
  }
}

// ---------------- k_gru16: r13 structure, slimmed serial chain ---------------
// wg 0..5 : CELL. Changes vs r13: (1) gate MFMA chains split 2+2 (depth 2,
//           -2 MFMA latencies on serial path); (2) l==2 stores out DIRECTLY
//           per step (fire-and-forget; no SL stage, no chunk flush/drain);
//           (3) l==0 prefetch continuous across chunks (no poll, no bubble).
// wg 6..37: GX (r12-proven chunk GEMM, unchanged). Heater removed (null).
__global__ __launch_bounds__(512, 1) void k_gru16(
    const _Float16* __restrict__ Wx, const _Float16* __restrict__ Wh,
    const float* __restrict__ gi0, float* __restrict__ gi1,
    float* __restrict__ gi2, const float* __restrict__ bih,
    const float* __restrict__ bhh, unsigned long long* Hbuf,
    float* __restrict__ out, unsigned* flags)
{
  const int wg = blockIdx.x;
  const int tid = threadIdx.x;
  const int w = tid >> 6, lane = tid & 63;
  const int lo = lane & 15, hi = lane >> 4;

  __shared__ char LDSU[36864];   // cell: SL 32K + hlds 4K ; gx: XL 32K

  if (wg < 6) {
    // ======================= CELL role =======================
    const int c = wg, l = c >> 1, d = c & 1;
    _Float16* hlds = (_Float16*)(LDSU + 32768);   // [2][8*128]
    char* SL = LDSU;

    { f16x8 z = {0,0,0,0,0,0,0,0};
      for (int p = tid; p < 256; p += 512) ((f16x8*)hlds)[p] = z; }

    f16x8 bh[3][4];
    #pragma unroll
    for (int nt = 0; nt < 3; ++nt) {
      int o = 16*(w + 8*nt) + lo;
      #pragma unroll
      for (int ks = 0; ks < 4; ++ks)
        bh[nt][ks] = *(const f16x8*)(Wh + ((size_t)c*384 + o)*128 + 32*ks + 8*hi);
    }
    #pragma unroll
    for (int nt = 0; nt < 3; ++nt)
      #pragma unroll
      for (int ks = 0; ks < 4; ++ks)
        PIN(bh[nt][ks]);

    const int hidx = 16*w + lo;
    const float b_hn = bhh[(size_t)c*384 + 256 + hidx];
    const int b0 = 4*(hi & 1);

    const float* gplain = gi0 + (size_t)d*384*8;              // l==0 path
    const unsigned long long* gatom =                          // l>0 path
        (const unsigned long long*)((l == 1) ? gi1 : gi2) + (size_t)(d*384)*4;
    unsigned* fg = flags + 8 + (l > 0 ? (l-1)*32 : 0);

    f32x4 gA0,gA1,gA2, gB0,gB1,gB2;
    auto LD = [&](int t, f32x4& x0, f32x4& x1, f32x4& x2) {
      if (l == 0) {
        const float* g = gplain + (size_t)t*768*8;
        x0 = *(const f32x4*)(g + (size_t)hidx*8 + b0);
        x1 = *(const f32x4*)(g + ((size_t)128 + hidx)*8 + b0);
        x2 = *(const f32x4*)(g + ((size_t)256 + hidx)*8 + b0);
      } else {
        const unsigned long long* g = gatom + (size_t)t*3072 + (b0 >> 1);
        #pragma unroll
        for (int a = 0; a < 3; ++a) {
          size_t ix = (size_t)(a*128 + hidx)*4;
          unsigned long long u0 = __hip_atomic_load(g + ix,
              __ATOMIC_RELAXED, __HIP_MEMORY_SCOPE_AGENT);
          unsigned long long u1 = __hip_atomic_load(g + ix + 1,
              __ATOMIC_RELAXED, __HIP_MEMORY_SCOPE_AGENT);
          f32x4 v;
          ((unsigned long long*)&v)[0] = u0;
          ((unsigned long long*)&v)[1] = u1;
          if (a == 0) x0 = v; else if (a == 1) x1 = v; else x2 = v;
        }
      }
    };

    float hp[4] = {0,0,0,0};
    __syncthreads();

    if (l == 0) {   // continuous prefetch; gi0 fully materialized already
      LD(0, gA0, gA1, gA2);
      LD(1, gB0, gB1, gB2);
    }

    for (int tc = 0; tc < NCHUNK; ++tc) {
      if (l > 0) {
        if (tid == 0) {
          while (__hip_atomic_load(fg + tc, __ATOMIC_RELAXED,
                                   __HIP_MEMORY_SCOPE_AGENT) == 0u)
            __builtin_amdgcn_s_sleep(2);
          __builtin_amdgcn_fence(__ATOMIC_ACQUIRE, "agent");
        }
        __syncthreads();
        LD(tc*CHUNK,     gA0, gA1, gA2);
        LD(tc*CHUNK + 1, gB0, gB1, gB2);
      }

      #pragma unroll
      for (int tt = 0; tt < CHUNK; ++tt) {
        const int t = tc*CHUNK + tt;
        f32x4 ax0, ax1, ax2;
        const bool more = (tt + 2 < CHUNK) || (l == 0 && t + 2 < T_LEN);
        if (!(tt & 1)) {
          ax0 = gA0; ax1 = gA1; ax2 = gA2;
          if (more) LD(t + 2, gA0, gA1, gA2);
        } else {
          ax0 = gB0; ax1 = gB1; ax2 = gB2;
          if (more) LD(t + 2, gB0, gB1, gB2);
        }
        // h-part MFMAs: 2+2 split accumulators (serial depth 2, not 4)
        f32x4 ah0 = {0,0,0,0}, ah1 = {0,0,0,0}, ah2 = {0,0,0,0};
        f32x4 bh0 = {0,0,0,0}, bh1 = {0,0,0,0}, bh2 = {0,0,0,0};
        {
          const char* hb = (const char*)hlds + (t & 1)*2048;
          f16x8 a[4];
          #pragma unroll
          for (int ks = 0; ks < 4; ++ks) {
            int byte = ((lo & 7)*256 + (32*ks + 8*hi)*2) ^ ((lo & 7) << 4);
            a[ks] = *(const f16x8*)(hb + byte);
          }
          ah0 = MFMA16(a[0], bh[0][0], ah0);
          ah1 = MFMA16(a[0], bh[1][0], ah1);
          ah2 = MFMA16(a[0], bh[2][0], ah2);
          bh0 = MFMA16(a[2], bh[0][2], bh0);
          bh1 = MFMA16(a[2], bh[1][2], bh1);
          bh2 = MFMA16(a[2], bh[2][2], bh2);
          ah0 = MFMA16(a[1], bh[0][1], ah0);
          ah1 = MFMA16(a[1], bh[1][1], ah1);
          ah2 = MFMA16(a[1], bh[2][1], ah2);
          bh0 = MFMA16(a[3], bh[0][3], bh0);
          bh1 = MFMA16(a[3], bh[1][3], bh1);
          bh2 = MFMA16(a[3], bh[2][3], bh2);
          ah0 += bh0; ah1 += bh1; ah2 += bh2;
        }
        // slim combine
        float hn[4];
        #pragma unroll
        for (int q = 0; q < 4; ++q) {
          float r  = fsig(ax0[q] + ah0[q]);
          float z  = fsig(ax1[q] + ah1[q]);
          float nn = ftanhf(fmaf(r, ah2[q] + b_hn, ax2[q]));
          hn[q] = fmaf(z, hp[q] - nn, nn);
          hp[q] = hn[q];
        }
        // write h (+ stage l<2 / direct-store l==2)
        if (lane < 32) {
          char* hb2 = (char*)hlds + ((t + 1) & 1)*2048;
          #pragma unroll
          for (int q = 0; q < 4; ++q) {
            int b = 4*hi + q;
            int byte = (b*256 + hidx*2) ^ (b << 4);
            *(_Float16*)(hb2 + byte) = (_Float16)hn[q];
            if (l < 2) *(_Float16*)(SL + (tt*8 + b)*256 + hidx*2) = (_Float16)hn[q];
            else       out[((size_t)b*256 + t)*256 + d*128 + hidx] = hn[q];
          }
        }
        asm volatile("s_waitcnt lgkmcnt(0)" ::: "memory");
        __builtin_amdgcn_s_barrier();
        __builtin_amdgcn_sched_barrier(0);
      }

      // chunk flush (producers only; l==2 already stored out directly)
      if (l < 2) {
        #pragma unroll
        for (int i = 0; i < 4; ++i) {
          int u = i*512 + tid;                  // 2048 8B units
          int tt2 = u >> 8, b = (u >> 5) & 7, pu = u & 31;
          unsigned long long v = *(const unsigned long long*)
              (SL + (tt2*8 + b)*256 + pu*8);
          __hip_atomic_store(Hbuf + (((size_t)c) << 16)
                                  + (size_t)(tc*CHUNK + tt2)*256 + b*32 + pu,
                             v, __ATOMIC_RELAXED, __HIP_MEMORY_SCOPE_AGENT);
        }
        asm volatile("s_waitcnt vmcnt(0)" ::: "memory");
        __syncthreads();
        if (tid == 0)
          __hip_atomic_store(flags + c, (unsigned)(tc + 1),
                             __ATOMIC_RELEASE, __HIP_MEMORY_SCOPE_AGENT);
      }
    }
  } else {
    // ======================= GX role =======================
    const int g  = wg - 6;
    const int lg = 1 + (g >> 4);          // target layer 1 or 2
    const int cinf = (lg - 1) * 2;        // source cells
    unsigned long long* gdst = (unsigned long long*)((lg == 1) ? gi1 : gi2);
    unsigned* fg = flags + 8 + (lg - 1)*32;
    _Float16* XL = (_Float16*)LDSU;

    for (int rep = 0; rep < 2; ++rep) {
      const int tc = (g & 15) + rep*16;
      const int t0 = tc * CHUNK;
      if (tid == 0) {
        while (__hip_atomic_load(flags + cinf, __ATOMIC_RELAXED,
                                 __HIP_MEMORY_SCOPE_AGENT) <= (unsigned)tc)
          __builtin_amdgcn_s_sleep(8);
        while (__hip_atomic_load(flags + cinf + 1, __ATOMIC_RELAXED,
                                 __HIP_MEMORY_SCOPE_AGENT) <= (unsigned)tc)
          __builtin_amdgcn_s_sleep(8);
        __builtin_amdgcn_fence(__ATOMIC_ACQUIRE, "agent");
      }
      __syncthreads();
      #pragma unroll
      for (int r = 0; r < 8; ++r) {
        int u = r*512 + tid;                  // 4096 8B units
        int cell = u >> 11, rem = u & 2047;
        int tt = rem >> 8, b = (rem >> 5) & 7, p = rem & 31;
        unsigned long long v = __hip_atomic_load(
            Hbuf + (((size_t)(cinf + cell)) << 16)
                 + (size_t)(t0 + tt)*256 + b*32 + p,
            __ATOMIC_RELAXED, __HIP_MEMORY_SCOPE_AGENT);
        int byte = (tt*4096 + b*512 + cell*256 + p*8) ^ ((b & 7) << 4);
        *(unsigned long long*)((char*)XL + byte) = v;
      }
      __syncthreads();

      f32x4 acc[2][3][4];
      #pragma unroll
      for (int c2 = 0; c2 < 2; ++c2)
        #pragma unroll
        for (int nt = 0; nt < 3; ++nt)
          #pragma unroll
          for (int mt = 0; mt < 4; ++mt) acc[c2][nt][mt] = (f32x4){0,0,0,0};

      for (int ks = 0; ks < 8; ++ks) {
        f16x8 a[4];
        #pragma unroll
        for (int mt = 0; mt < 4; ++mt) {
          int byte = ((mt*2 + (lo >> 3))*4096 + (lo & 7)*512 + 64*ks + 16*hi)
                     ^ ((lo & 7) << 4);
          a[mt] = *(const f16x8*)((const char*)XL + byte);
        }
        #pragma unroll
        for (int c2 = 0; c2 < 2; ++c2) {
          const size_t wb = (size_t)(2*lg + c2 - 2) * 384;
          #pragma unroll
          for (int nt = 0; nt < 3; ++nt) {
            f16x8 bw = *(const f16x8*)(Wx + (wb + 16*(w + 8*nt) + lo)*256
                                          + 32*ks + 8*hi);
            #pragma unroll
            for (int mt = 0; mt < 4; ++mt)
              acc[c2][nt][mt] = MFMA16(a[mt], bw, acc[c2][nt][mt]);
          }
        }
      }
      // bias epilogue + gi stores
      #pragma unroll
      for (int c2 = 0; c2 < 2; ++c2) {
        const int c = 2*lg + c2;
        #pragma unroll
        for (int nt = 0; nt < 3; ++nt) {
          int o = 16*(w + 8*nt) + lo;           // 0..383 gate-local
          float badd = bih[(size_t)c*384 + o]
                     + ((o < 256) ? bhh[(size_t)c*384 + o] : 0.f);
          #pragma unroll
          for (int mt = 0; mt < 4; ++mt) {
            f32x4 v = acc[c2][nt][mt];
            v[0] += badd; v[1] += badd; v[2] += badd; v[3] += badd;
            int t = t0 + mt*2 + (hi >> 1), b0i = 4*(hi & 1);
            size_t ix = (size_t)t*3072 + (size_t)(c2*384 + o)*4 + (b0i >> 1);
            __hip_atomic_store(gdst + ix,     ((unsigned long long*)&v)[0],
                               __ATOMIC_RELAXED, __HIP_MEMORY_SCOPE_AGENT);
            __hip_atomic_store(gdst + ix + 1, ((unsigned long long*)&v)[1],
                               __ATOMIC_RELAXED, __HIP_MEMORY_SCOPE_AGENT);
          }
        }
      }
      asm volatile("s_waitcnt vmcnt(0)" ::: "memory");
      __syncthreads();
      if (tid == 0)
        __hip_atomic_store(fg + tc, 1u,
                           __ATOMIC_RELEASE, __HIP_MEMORY_SCOPE_AGENT);
      __syncthreads();   // XL WAR before next rep
    }
  }
}

extern "C" void kernel_launch(void* const* d_in, const int* in_sizes, int n_in,
                              void* d_out, int out_size, void* d_ws, size_t ws_size,
                              hipStream_t stream) {
  (void)in_sizes; (void)n_in; (void)out_size; (void)ws_size;
  const float* P     = (const float*)d_in[0];
  const float* vw    = (const float*)d_in[2];
  const float* WvP   = (const float*)d_in[3];
  const float* WvPb  = (const float*)d_in[4];
  const float* gatew = (const float*)d_in[5];
  const float* Wih   = (const float*)d_in[6];
  const float* Whh   = (const float*)d_in[7];
  const float* bih   = (const float*)d_in[8];
  const float* bhh   = (const float*)d_in[9];
  float* out = (float*)d_out;

  char* wsp = (char*)d_ws;
  size_t off = 0;
  auto alloc = [&](size_t nbytes) -> void* {
    void* p = wsp + off;
    off += (nbytes + 255) & ~(size_t)255;
    return p;
  };
  float*    prepT = (float*)   alloc((size_t)8*128*256*4);
  float*    pbar  = (float*)   alloc((size_t)256*8*128*4);
  float*    ug    = (float*)   alloc((size_t)256*8*256*4);
  float*    gi0   = (float*)   alloc((size_t)256*768*8*4);   // [t][o][b]
  float*    gi1   = (float*)   alloc((size_t)256*768*8*4);
  float*    gi2   = (float*)   alloc((size_t)256*768*8*4);
  unsigned long long* Hbuf = (unsigned long long*)alloc((size_t)4*256*8*32*8);
  _Float16* Wx    = (_Float16*)alloc((size_t)4*384*256*2);
  _Float16* Wh    = (_Float16*)alloc((size_t)6*384*128*2);
  float*    WvPT  = (float*)   alloc((size_t)256*128*4);
  float*    WvPbT = (float*)   alloc((size_t)256*128*4);
  float*    gwT   = (float*)   alloc((size_t)256*256*4);
  float*    Wih0T = (float*)   alloc((size_t)256*768*4);
  unsigned* flags = (unsigned*)alloc((size_t)128*4);

  hipLaunchKernelGGL(k_prep, dim3(256), dim3(256), 0, stream,
                     WvP, WvPb, gatew, Wih, Whh, WvPT, WvPbT, gwT, Wih0T, Wx, Wh,
                     flags);
  hipLaunchKernelGGL(k_prep_pbar, dim3(512), dim3(256), 0, stream,
                     P, WvPT, WvPbT, prepT, pbar);
  hipLaunchKernelGGL(k_attn, dim3(512), dim3(256), 0, stream,
                     prepT, pbar, vw, gwT, ug);
  hipLaunchKernelGGL(k_gi0, dim3(256), dim3(256), 0, stream,
                     ug, Wih0T, bih, bhh, gi0);
  hipLaunchKernelGGL(k_gru16, dim3(38), dim3(512), 0, stream,
                     Wx, Wh, gi0, gi1, gi2, bih, bhh, Hbuf, out, flags);
}

// Round 18
// 449.645 us; speedup vs baseline: 1.1188x; 1.0076x over previous
//
#include <hip/hip_runtime.h>
#include <hip/hip_bf16.h>

// Problem dims (fixed): T=256, B=8, H=128, IN=256
#define T_LEN 256
#define CHUNK 8
#define NCHUNK (T_LEN / CHUNK)

typedef _Float16 f16x8 __attribute__((ext_vector_type(8)));
typedef float f32x4 __attribute__((ext_vector_type(4)));

__device__ __forceinline__ float fsig(float x) {
  return __builtin_amdgcn_rcpf(1.f + __expf(-x));
}
__device__ __forceinline__ float ftanhf(float x) {
  return fmaf(-2.f, __builtin_amdgcn_rcpf(1.f + __expf(2.f * x)), 1.f);
}

#define MFMA16(a,b,c) __builtin_amdgcn_mfma_f32_16x16x32_f16(a, b, c, 0, 0, 0)
#define PIN(x) asm volatile("" : "+v"(*reinterpret_cast<f32x4*>(&(x))))

// ---------------- weight reformat (+ flag zero) ----------------
__global__ void k_prep(const float* __restrict__ WvP, const float* __restrict__ WvPb,
                       const float* __restrict__ gatew,
                       const float* __restrict__ Wih, const float* __restrict__ Whh,
                       float* __restrict__ WvPT, float* __restrict__ WvPbT,
                       float* __restrict__ gwT, float* __restrict__ Wih0T,
                       _Float16* __restrict__ Wx, _Float16* __restrict__ Wh,
                       unsigned* __restrict__ flags) {
  int n = blockIdx.x*blockDim.x + threadIdx.x;
  int NT = gridDim.x*blockDim.x;
  if (n < 128) flags[n] = 0u;
  for (int k = n; k < 256*128; k += NT) {
    int i = k >> 7, h = k & 127;
    WvPT[k]  = WvP[h*256 + i];
    WvPbT[k] = WvPb[h*256 + i];
  }
  for (int k = n; k < 256*256; k += NT) {
    int dd = k >> 8, e = k & 255;
    gwT[k] = gatew[e*256 + dd];
  }
  for (int k = n; k < 256*768; k += NT) {
    int i = k / 768, doo = k % 768;
    Wih0T[k] = Wih[(size_t)doo*256 + i];
  }
  for (int k = n; k < 6*384*128; k += NT) {
    Wh[k] = (_Float16)Whh[k];           // flat [c][o][128]
  }
  for (int k = n; k < 4*384*256; k += NT) {
    Wx[k] = (_Float16)Wih[(size_t)2*384*256 + k];  // cells 2..5
  }
}

// ---------------- prep/pbar projections ----------------
__global__ __launch_bounds__(256) void k_prep_pbar(
    const float* __restrict__ P, const float* __restrict__ WvPT,
    const float* __restrict__ WvPbT, float* __restrict__ prepT,
    float* __restrict__ pbar) {
  __shared__ float Pl[4*256];
  int R0 = blockIdx.x * 4, tid = threadIdx.x;
  for (int k = tid; k < 1024; k += 256) Pl[k] = P[(size_t)R0*256 + k];
  __syncthreads();
  int h = tid & 127;
  const float* Wt = (tid < 128) ? WvPT : WvPbT;
  float acc[4] = {0,0,0,0};
  for (int i = 0; i < 256; ++i) {
    float w = Wt[i*128 + h];
    acc[0] += Pl[i]*w; acc[1] += Pl[256+i]*w;
    acc[2] += Pl[512+i]*w; acc[3] += Pl[768+i]*w;
  }
  #pragma unroll
  for (int r = 0; r < 4; ++r) {
    int R = R0 + r, t = R >> 3, b = R & 7;
    if (tid < 128) prepT[((size_t)b*128 + h)*256 + t] = acc[r];
    else           pbar[(size_t)R*128 + h] = acc[r];
  }
}

// ---------------- fused attention + gate (division-free) ----------------
__global__ __launch_bounds__(256) void k_attn(
    const float* __restrict__ prepT, const float* __restrict__ pbar,
    const float* __restrict__ vw, const float* __restrict__ gwT,
    float* __restrict__ ug) {
  int b = blockIdx.x & 7, q0 = (blockIdx.x >> 3) * 4;
  int tid = threadIdx.x;
  __shared__ float u[4][256];
  __shared__ float vl[128];
  __shared__ float sc[4][256];
  __shared__ float red[4];
  if (tid < 128) vl[tid] = vw[tid];
  for (int k = tid; k < 512; k += 256) {
    int j = k >> 7, h = k & 127;
    u[j][h] = pbar[(((size_t)(q0+j))*8 + b)*128 + h];
  }
  __syncthreads();
  float s[4] = {0,0,0,0};
  for (int h = 0; h < 128; ++h) {
    float pk = prepT[((size_t)b*128 + h)*256 + tid];
    float vh = vl[h];
    #pragma unroll
    for (int j = 0; j < 4; ++j) {
      float e = __expf(2.f*(u[j][h] + pk));
      float t = __builtin_amdgcn_rcpf(e + 1.f);      // tanh = 1-2t
      s[j] = fmaf(vh, fmaf(-2.f, t, 1.f), s[j]);
    }
  }
  #pragma unroll
  for (int j = 0; j < 4; ++j) {
    float v = s[j];
    #pragma unroll
    for (int off = 32; off > 0; off >>= 1) v = fmaxf(v, __shfl_xor(v, off));
    if ((tid & 63) == 0) red[tid >> 6] = v;
    __syncthreads();
    float m = fmaxf(fmaxf(red[0], red[1]), fmaxf(red[2], red[3]));
    __syncthreads();
    float e = __expf(s[j] - m);
    v = e;
    #pragma unroll
    for (int off = 32; off > 0; off >>= 1) v += __shfl_xor(v, off);
    if ((tid & 63) == 0) red[tid >> 6] = v;
    __syncthreads();
    float sum = red[0] + red[1] + red[2] + red[3];
    __syncthreads();
    sc[j][tid] = e * __builtin_amdgcn_rcpf(sum);
  }
  __syncthreads();
  {
    int h = tid & 127, jj = tid >> 7;
    float c0 = 0.f, c1 = 0.f;
    for (int k = 0; k < 256; ++k) {
      float p = pbar[((size_t)k*8 + b)*128 + h];
      c0 += sc[jj][k]   * p;
      c1 += sc[jj+2][k] * p;
    }
    u[jj][128+h]   = c0;
    u[jj+2][128+h] = c1;
  }
  __syncthreads();
  {
    float gg[4] = {0,0,0,0};
    for (int dd = 0; dd < 256; ++dd) {
      float w = gwT[(size_t)dd*256 + tid];
      #pragma unroll
      for (int j = 0; j < 4; ++j) gg[j] += u[j][dd] * w;
    }
    #pragma unroll
    for (int j = 0; j < 4; ++j) {
      float ue = u[j][tid];
      ug[(((size_t)(q0+j))*8 + b)*256 + tid] = ue * fsig(gg[j]);
    }
  }
}

// ---------------- gi0 = ug @ Wih0^T + bih (+bhh for r,z) : [t][768][8] -------
__global__ __launch_bounds__(256) void k_gi0(
    const float* __restrict__ ug, const float* __restrict__ Wih0T,
    const float* __restrict__ bih, const float* __restrict__ bhh,
    float* __restrict__ gi0) {
  __shared__ float ul[8][256];
  __shared__ float st[768*8];
  int t = blockIdx.x, tid = threadIdx.x;
  for (int k = tid; k < 2048; k += 256) ul[k >> 8][k & 255] = ug[(size_t)t*2048 + k];
  __syncthreads();
  float acc[3][8];
  #pragma unroll
  for (int a = 0; a < 3; ++a)
    #pragma unroll
    for (int r = 0; r < 8; ++r) acc[a][r] = 0.f;
  for (int i = 0; i < 256; ++i) {
    float w0 = Wih0T[(size_t)i*768 + tid];
    float w1 = Wih0T[(size_t)i*768 + 256 + tid];
    float w2 = Wih0T[(size_t)i*768 + 512 + tid];
    #pragma unroll
    for (int r = 0; r < 8; ++r) {
      float uu = ul[r][i];
      acc[0][r] += uu*w0; acc[1][r] += uu*w1; acc[2][r] += uu*w2;
    }
  }
  #pragma unroll
  for (int a = 0; a < 3; ++a) {
    int o = a*256 + tid;
    int og = (o >= 384) ? (o - 384) : o;               // gate-local (r10 fix)
    float ba = bih[o] + ((og < 256) ? bhh[o] : 0.f);   // fold bhh for r,z
    #pragma unroll
    for (int r = 0; r < 8; ++r) st[o*8 + r] = acc[a][r] + ba;
  }
  __syncthreads();
  #pragma unroll
  for (int j = 0; j < 6; ++j) {
    int idx = j*256 + tid;
    ((f32x4*)gi0)[(size_t)t*1536 + idx] = ((const f32x4*)st)[idx];
  }
}

// ---------------- k_gru18: r17 + per-step h publish (no flush burst) ---------
// wg 0..5 : CELL. vs r17: l<2 publishes h(t) DIRECTLY per step (plain 2B
//           stores, fire-and-forget; raw s_barrier emits no vmcnt drain —
//           proven by r16/r17's l==2 direct out stores). Chunk-end is just
//           {vmcnt(0) on long-retired stores + barrier + flag}. SL staging
//           and the 16KB flush burst are gone from the serial path.
// wg 6..37: GX (r12-proven chunk GEMM, unchanged).
__global__ __launch_bounds__(512, 1) void k_gru18(
    const _Float16* __restrict__ Wx, const _Float16* __restrict__ Wh,
    const float* __restrict__ gi0, float* __restrict__ gi1,
    float* __restrict__ gi2, const float* __restrict__ bih,
    const float* __restrict__ bhh, unsigned long long* Hbuf,
    float* __restrict__ out, unsigned* flags)
{
  const int wg = blockIdx.x;
  const int tid = threadIdx.x;
  const int w = tid >> 6, lane = tid & 63;
  const int lo = lane & 15, hi = lane >> 4;

  __shared__ char LDSU[36864];   // cell: hlds @32K ; gx: XL 32K

  if (wg < 6) {
    // ======================= CELL role =======================
    const int c = wg, l = c >> 1, d = c & 1;
    _Float16* hlds = (_Float16*)(LDSU + 32768);   // [2][8*128]

    { f16x8 z = {0,0,0,0,0,0,0,0};
      for (int p = tid; p < 256; p += 512) ((f16x8*)hlds)[p] = z; }

    f16x8 bh[3][4];
    #pragma unroll
    for (int nt = 0; nt < 3; ++nt) {
      int o = 16*(w + 8*nt) + lo;
      #pragma unroll
      for (int ks = 0; ks < 4; ++ks)
        bh[nt][ks] = *(const f16x8*)(Wh + ((size_t)c*384 + o)*128 + 32*ks + 8*hi);
    }
    #pragma unroll
    for (int nt = 0; nt < 3; ++nt)
      #pragma unroll
      for (int ks = 0; ks < 4; ++ks)
        PIN(bh[nt][ks]);

    const int hidx = 16*w + lo;
    const float b_hn = bhh[(size_t)c*384 + 256 + hidx];
    const int b0 = 4*(hi & 1);

    const float* gplain = gi0 + (size_t)d*384*8;              // l==0 path
    const unsigned long long* gatom =                          // l>0 path
        (const unsigned long long*)((l == 1) ? gi1 : gi2) + (size_t)(d*384)*4;
    unsigned* fg = flags + 8 + (l > 0 ? (l-1)*32 : 0);
    _Float16* Hg = (_Float16*)Hbuf;                            // f16 view

    f32x4 gA0,gA1,gA2, gB0,gB1,gB2;
    auto LD = [&](int t, f32x4& x0, f32x4& x1, f32x4& x2) {
      if (l == 0) {
        const float* g = gplain + (size_t)t*768*8;
        x0 = *(const f32x4*)(g + (size_t)hidx*8 + b0);
        x1 = *(const f32x4*)(g + ((size_t)128 + hidx)*8 + b0);
        x2 = *(const f32x4*)(g + ((size_t)256 + hidx)*8 + b0);
      } else {
        const unsigned long long* g = gatom + (size_t)t*3072 + (b0 >> 1);
        #pragma unroll
        for (int a = 0; a < 3; ++a) {
          size_t ix = (size_t)(a*128 + hidx)*4;
          unsigned long long u0 = __hip_atomic_load(g + ix,
              __ATOMIC_RELAXED, __HIP_MEMORY_SCOPE_AGENT);
          unsigned long long u1 = __hip_atomic_load(g + ix + 1,
              __ATOMIC_RELAXED, __HIP_MEMORY_SCOPE_AGENT);
          f32x4 v;
          ((unsigned long long*)&v)[0] = u0;
          ((unsigned long long*)&v)[1] = u1;
          if (a == 0) x0 = v; else if (a == 1) x1 = v; else x2 = v;
        }
      }
    };

    float hp[4] = {0,0,0,0};
    __syncthreads();

    if (l == 0) {   // continuous prefetch; gi0 fully materialized already
      LD(0, gA0, gA1, gA2);
      LD(1, gB0, gB1, gB2);
    }

    for (int tc = 0; tc < NCHUNK; ++tc) {
      if (l > 0) {
        if (tid == 0) {
          while (__hip_atomic_load(fg + tc, __ATOMIC_RELAXED,
                                   __HIP_MEMORY_SCOPE_AGENT) == 0u)
            __builtin_amdgcn_s_sleep(2);
          __builtin_amdgcn_fence(__ATOMIC_ACQUIRE, "agent");
        }
        __syncthreads();
        LD(tc*CHUNK,     gA0, gA1, gA2);
        LD(tc*CHUNK + 1, gB0, gB1, gB2);
      }

      #pragma unroll
      for (int tt = 0; tt < CHUNK; ++tt) {
        const int t = tc*CHUNK + tt;
        f32x4 ax0, ax1, ax2;
        const bool more = (tt + 2 < CHUNK) || (l == 0 && t + 2 < T_LEN);
        if (!(tt & 1)) {
          ax0 = gA0; ax1 = gA1; ax2 = gA2;
          if (more) LD(t + 2, gA0, gA1, gA2);
        } else {
          ax0 = gB0; ax1 = gB1; ax2 = gB2;
          if (more) LD(t + 2, gB0, gB1, gB2);
        }
        // h-part MFMAs: 2+2 split accumulators
        f32x4 ah0 = {0,0,0,0}, ah1 = {0,0,0,0}, ah2 = {0,0,0,0};
        f32x4 bh0 = {0,0,0,0}, bh1 = {0,0,0,0}, bh2 = {0,0,0,0};
        {
          const char* hb = (const char*)hlds + (t & 1)*2048;
          f16x8 a[4];
          #pragma unroll
          for (int ks = 0; ks < 4; ++ks) {
            int byte = ((lo & 7)*256 + (32*ks + 8*hi)*2) ^ ((lo & 7) << 4);
            a[ks] = *(const f16x8*)(hb + byte);
          }
          ah0 = MFMA16(a[0], bh[0][0], ah0);
          ah1 = MFMA16(a[0], bh[1][0], ah1);
          ah2 = MFMA16(a[0], bh[2][0], ah2);
          bh0 = MFMA16(a[2], bh[0][2], bh0);
          bh1 = MFMA16(a[2], bh[1][2], bh1);
          bh2 = MFMA16(a[2], bh[2][2], bh2);
          ah0 = MFMA16(a[1], bh[0][1], ah0);
          ah1 = MFMA16(a[1], bh[1][1], ah1);
          ah2 = MFMA16(a[1], bh[2][1], ah2);
          bh0 = MFMA16(a[3], bh[0][3], bh0);
          bh1 = MFMA16(a[3], bh[1][3], bh1);
          bh2 = MFMA16(a[3], bh[2][3], bh2);
          ah0 += bh0; ah1 += bh1; ah2 += bh2;
        }
        // slim combine
        float hn[4];
        #pragma unroll
        for (int q = 0; q < 4; ++q) {
          float r  = fsig(ax0[q] + ah0[q]);
          float z  = fsig(ax1[q] + ah1[q]);
          float nn = ftanhf(fmaf(r, ah2[q] + b_hn, ax2[q]));
          hn[q] = fmaf(z, hp[q] - nn, nn);
          hp[q] = hn[q];
        }
        // write h; per-step direct publish (l<2) / direct out (l==2)
        if (lane < 32) {
          char* hb2 = (char*)hlds + ((t + 1) & 1)*2048;
          #pragma unroll
          for (int q = 0; q < 4; ++q) {
            int b = 4*hi + q;
            int byte = (b*256 + hidx*2) ^ (b << 4);
            *(_Float16*)(hb2 + byte) = (_Float16)hn[q];
            if (l < 2)
              Hg[(((size_t)c) << 18) + (size_t)t*1024 + b*128 + hidx] =
                  (_Float16)hn[q];
            else
              out[((size_t)b*256 + t)*256 + d*128 + hidx] = hn[q];
          }
        }
        asm volatile("s_waitcnt lgkmcnt(0)" ::: "memory");
        __builtin_amdgcn_s_barrier();
        __builtin_amdgcn_sched_barrier(0);
      }

      // chunk end (producers): drain (mostly retired) + flag
      if (l < 2) {
        asm volatile("s_waitcnt vmcnt(0)" ::: "memory");
        __syncthreads();
        if (tid == 0)
          __hip_atomic_store(flags + c, (unsigned)(tc + 1),
                             __ATOMIC_RELEASE, __HIP_MEMORY_SCOPE_AGENT);
      }
    }
  } else {
    // ======================= GX role =======================
    const int g  = wg - 6;
    const int lg = 1 + (g >> 4);          // target layer 1 or 2
    const int cinf = (lg - 1) * 2;        // source cells
    unsigned long long* gdst = (unsigned long long*)((lg == 1) ? gi1 : gi2);
    unsigned* fg = flags + 8 + (lg - 1)*32;
    _Float16* XL = (_Float16*)LDSU;

    for (int rep = 0; rep < 2; ++rep) {
      const int tc = (g & 15) + rep*16;
      const int t0 = tc * CHUNK;
      if (tid == 0) {
        while (__hip_atomic_load(flags + cinf, __ATOMIC_RELAXED,
                                 __HIP_MEMORY_SCOPE_AGENT) <= (unsigned)tc)
          __builtin_amdgcn_s_sleep(8);
        while (__hip_atomic_load(flags + cinf + 1, __ATOMIC_RELAXED,
                                 __HIP_MEMORY_SCOPE_AGENT) <= (unsigned)tc)
          __builtin_amdgcn_s_sleep(8);
        __builtin_amdgcn_fence(__ATOMIC_ACQUIRE, "agent");
      }
      __syncthreads();
      #pragma unroll
      for (int r = 0; r < 8; ++r) {
        int u = r*512 + tid;                  // 4096 8B units
        int cell = u >> 11, rem = u & 2047;
        int tt = rem >> 8, b = (rem >> 5) & 7, p = rem & 31;
        unsigned long long v = __hip_atomic_load(
            Hbuf + (((size_t)(cinf + cell)) << 16)
                 + (size_t)(t0 + tt)*256 + b*32 + p,
            __ATOMIC_RELAXED, __HIP_MEMORY_SCOPE_AGENT);
        int byte = (tt*4096 + b*512 + cell*256 + p*8) ^ ((b & 7) << 4);
        *(unsigned long long*)((char*)XL + byte) = v;
      }
      __syncthreads();

      f32x4 acc[2][3][4];
      #pragma unroll
      for (int c2 = 0; c2 < 2; ++c2)
        #pragma unroll
        for (int nt = 0; nt < 3; ++nt)
          #pragma unroll
          for (int mt = 0; mt < 4; ++mt) acc[c2][nt][mt] = (f32x4){0,0,0,0};

      for (int ks = 0; ks < 8; ++ks) {
        f16x8 a[4];
        #pragma unroll
        for (int mt = 0; mt < 4; ++mt) {
          int byte = ((mt*2 + (lo >> 3))*4096 + (lo & 7)*512 + 64*ks + 16*hi)
                     ^ ((lo & 7) << 4);
          a[mt] = *(const f16x8*)((const char*)XL + byte);
        }
        #pragma unroll
        for (int c2 = 0; c2 < 2; ++c2) {
          const size_t wb = (size_t)(2*lg + c2 - 2) * 384;
          #pragma unroll
          for (int nt = 0; nt < 3; ++nt) {
            f16x8 bw = *(const f16x8*)(Wx + (wb + 16*(w + 8*nt) + lo)*256
                                          + 32*ks + 8*hi);
            #pragma unroll
            for (int mt = 0; mt < 4; ++mt)
              acc[c2][nt][mt] = MFMA16(a[mt], bw, acc[c2][nt][mt]);
          }
        }
      }
      // bias epilogue + gi stores
      #pragma unroll
      for (int c2 = 0; c2 < 2; ++c2) {
        const int c = 2*lg + c2;
        #pragma unroll
        for (int nt = 0; nt < 3; ++nt) {
          int o = 16*(w + 8*nt) + lo;           // 0..383 gate-local
          float badd = bih[(size_t)c*384 + o]
                     + ((o < 256) ? bhh[(size_t)c*384 + o] : 0.f);
          #pragma unroll
          for (int mt = 0; mt < 4; ++mt) {
            f32x4 v = acc[c2][nt][mt];
            v[0] += badd; v[1] += badd; v[2] += badd; v[3] += badd;
            int t = t0 + mt*2 + (hi >> 1), b0i = 4*(hi & 1);
            size_t ix = (size_t)t*3072 + (size_t)(c2*384 + o)*4 + (b0i >> 1);
            __hip_atomic_store(gdst + ix,     ((unsigned long long*)&v)[0],
                               __ATOMIC_RELAXED, __HIP_MEMORY_SCOPE_AGENT);
            __hip_atomic_store(gdst + ix + 1, ((unsigned long long*)&v)[1],
                               __ATOMIC_RELAXED, __HIP_MEMORY_SCOPE_AGENT);
          }
        }
      }
      asm volatile("s_waitcnt vmcnt(0)" ::: "memory");
      __syncthreads();
      if (tid == 0)
        __hip_atomic_store(fg + tc, 1u,
                           __ATOMIC_RELEASE, __HIP_MEMORY_SCOPE_AGENT);
      __syncthreads();   // XL WAR before next rep
    }
  }
}

extern "C" void kernel_launch(void* const* d_in, const int* in_sizes, int n_in,
                              void* d_out, int out_size, void* d_ws, size_t ws_size,
                              hipStream_t stream) {
  (void)in_sizes; (void)n_in; (void)out_size; (void)ws_size;
  const float* P     = (const float*)d_in[0];
  const float* vw    = (const float*)d_in[2];
  const float* WvP   = (const float*)d_in[3];
  const float* WvPb  = (const float*)d_in[4];
  const float* gatew = (const float*)d_in[5];
  const float* Wih   = (const float*)d_in[6];
  const float* Whh   = (const float*)d_in[7];
  const float* bih   = (const float*)d_in[8];
  const float* bhh   = (const float*)d_in[9];
  float* out = (float*)d_out;

  char* wsp = (char*)d_ws;
  size_t off = 0;
  auto alloc = [&](size_t nbytes) -> void* {
    void* p = wsp + off;
    off += (nbytes + 255) & ~(size_t)255;
    return p;
  };
  float*    prepT = (float*)   alloc((size_t)8*128*256*4);
  float*    pbar  = (float*)   alloc((size_t)256*8*128*4);
  float*    ug    = (float*)   alloc((size_t)256*8*256*4);
  float*    gi0   = (float*)   alloc((size_t)256*768*8*4);   // [t][o][b]
  float*    gi1   = (float*)   alloc((size_t)256*768*8*4);
  float*    gi2   = (float*)   alloc((size_t)256*768*8*4);
  unsigned long long* Hbuf = (unsigned long long*)alloc((size_t)4*256*8*32*8);
  _Float16* Wx    = (_Float16*)alloc((size_t)4*384*256*2);
  _Float16* Wh    = (_Float16*)alloc((size_t)6*384*128*2);
  float*    WvPT  = (float*)   alloc((size_t)256*128*4);
  float*    WvPbT = (float*)   alloc((size_t)256*128*4);
  float*    gwT   = (float*)   alloc((size_t)256*256*4);
  float*    Wih0T = (float*)   alloc((size_t)256*768*4);
  unsigned* flags = (unsigned*)alloc((size_t)128*4);

  hipLaunchKernelGGL(k_prep, dim3(256), dim3(256), 0, stream,
                     WvP, WvPb, gatew, Wih, Whh, WvPT, WvPbT, gwT, Wih0T, Wx, Wh,
                     flags);
  hipLaunchKernelGGL(k_prep_pbar, dim3(512), dim3(256), 0, stream,
                     P, WvPT, WvPbT, prepT, pbar);
  hipLaunchKernelGGL(k_attn, dim3(512), dim3(256), 0, stream,
                     prepT, pbar, vw, gwT, ug);
  hipLaunchKernelGGL(k_gi0, dim3(256), dim3(256), 0, stream,
                     ug, Wih0T, bih, bhh, gi0);
  hipLaunchKernelGGL(k_gru18, dim3(38), dim3(512), 0, stream,
                     Wx, Wh, gi0, gi1, gi2, bih, bhh, Hbuf, out, flags);
}